// Round 1
// baseline (3360.725 us; speedup 1.0000x reference)
//
#include <hip/hip_runtime.h>
#include <math.h>

// Problem constants
#define L_LAYERS 4
#define B_G 128
#define S_G 128
#define N_N 16384      // B*S
#define E_E 262144
#define IN_F 64
#define HID 128
#define PE_F 16
#define HEADS 4
#define DK 32
#define OUT_F 10

// ---------------------------------------------------------------------------
// init: CSR-by-dst build
// ---------------------------------------------------------------------------
__global__ void zero_int_kernel(int* __restrict__ p, int n) {
    int i = blockIdx.x * 256 + threadIdx.x;
    if (i < n) p[i] = 0;
}

__global__ void hist_kernel(const int* __restrict__ dst, int* __restrict__ deg) {
    int e = blockIdx.x * 256 + threadIdx.x;
    if (e < E_E) atomicAdd(&deg[dst[e]], 1);
}

__global__ __launch_bounds__(1024) void scan_kernel(const int* __restrict__ deg,
                                                    int* __restrict__ row_ptr,
                                                    int* __restrict__ cursor) {
    __shared__ int lds[1024];
    int tid = threadIdx.x;
    int base = tid * 16;
    int d[16];
    int s = 0;
#pragma unroll
    for (int i = 0; i < 16; i++) { d[i] = deg[base + i]; s += d[i]; }
    lds[tid] = s;
    __syncthreads();
    for (int off = 1; off < 1024; off <<= 1) {
        int v = (tid >= off) ? lds[tid - off] : 0;
        __syncthreads();
        lds[tid] += v;
        __syncthreads();
    }
    int run = lds[tid] - s;  // exclusive prefix
#pragma unroll
    for (int i = 0; i < 16; i++) {
        row_ptr[base + i] = run;
        cursor[base + i] = run;
        run += d[i];
    }
    if (tid == 1023) row_ptr[N_N] = run;
}

__global__ void scatter_kernel(const int* __restrict__ src, const int* __restrict__ dst,
                               int* __restrict__ cursor, int* __restrict__ perm,
                               int* __restrict__ ssrc, int* __restrict__ sdst) {
    int e = blockIdx.x * 256 + threadIdx.x;
    if (e >= E_E) return;
    int dd = dst[e];
    int pos = atomicAdd(&cursor[dd], 1);
    perm[pos] = e;
    ssrc[pos] = src[e];
    sdst[pos] = dd;
}

__global__ void permute_kernel(const float* __restrict__ ea, const int* __restrict__ perm,
                               float* __restrict__ e) {
    int idx = blockIdx.x * 256 + threadIdx.x;  // E*32 float4s
    if (idx >= E_E * 32) return;
    int j = idx >> 5, c4 = idx & 31;
    const float4* sp = (const float4*)(ea + (long)perm[j] * HID);
    ((float4*)(e + (long)j * HID))[c4] = sp[c4];
}

// ---------------------------------------------------------------------------
// embed: h = [x@node_w+node_b | pe@pe_w+pe_b]
// ---------------------------------------------------------------------------
__global__ void embed_kernel(const float* __restrict__ x, const float* __restrict__ pe,
                             const float* __restrict__ node_w, const float* __restrict__ node_b,
                             const float* __restrict__ pe_w, const float* __restrict__ pe_b,
                             float* __restrict__ h) {
    int idx = blockIdx.x * 256 + threadIdx.x;
    if (idx >= N_N * HID) return;
    int i = idx >> 7, c = idx & 127;
    float acc;
    if (c < 112) {
        acc = node_b[c];
        const float* xr = x + (long)i * IN_F;
        for (int k = 0; k < IN_F; k++) acc += xr[k] * node_w[k * 112 + c];
    } else {
        int cc = c - 112;
        acc = pe_b[cc];
        const float* pr = pe + (long)i * PE_F;
        for (int k = 0; k < PE_F; k++) acc += pr[k] * pe_w[k * PE_F + cc];
    }
    h[idx] = acc;
}

// ---------------------------------------------------------------------------
// GEMM: C[M][128] = A[M][128] @ W[128][128] + bias  (MODE 1: += Dx[sdst]+Ex[ssrc])
// 256 thr, 32 rows/block, thread tile 2 rows x 8 cols. W staged in 2 k-halves
// (LDS 32KB W + 16.5KB A = 48.5KB -> 3 blocks/CU).
// ---------------------------------------------------------------------------
template <int MODE>
__global__ __launch_bounds__(256) void gemm128_kernel(
    const float* __restrict__ A, const float* __restrict__ W, const float* __restrict__ bias,
    float* __restrict__ Cout, const float* __restrict__ Dx, const float* __restrict__ Ex,
    const int* __restrict__ sdst, const int* __restrict__ ssrc) {
    __shared__ float w_lds[64 * 128];   // k-half
    __shared__ float a_lds[32 * 129];   // padded rows
    int tid = threadIdx.x;
    long rowBase = (long)blockIdx.x * 32;

    // stage A (32 x 128)
    const float4* Av = (const float4*)(A + rowBase * 128);
    for (int i = tid; i < 1024; i += 256) {
        float4 v = Av[i];
        int r = i >> 5, c4 = (i & 31) << 2;
        float* dp = &a_lds[r * 129 + c4];
        dp[0] = v.x; dp[1] = v.y; dp[2] = v.z; dp[3] = v.w;
    }

    int cg = tid & 15, rp = tid >> 4;
    int c0 = cg << 3, r0 = rp << 1;
    float acc[2][8];
#pragma unroll
    for (int r = 0; r < 2; r++)
#pragma unroll
        for (int j = 0; j < 8; j++) acc[r][j] = 0.f;

    for (int kp = 0; kp < 2; kp++) {
        __syncthreads();  // A staged (first iter) / w_lds free (second iter)
        const float4* Wv = (const float4*)(W + kp * 64 * 128);
        for (int i = tid; i < 2048; i += 256) ((float4*)w_lds)[i] = Wv[i];
        __syncthreads();
        const float* arow0 = &a_lds[r0 * 129 + kp * 64];
        const float* arow1 = arow0 + 129;
#pragma unroll 8
        for (int k = 0; k < 64; k++) {
            float a0 = arow0[k], a1 = arow1[k];
            const float4 w0 = *(const float4*)&w_lds[k * 128 + c0];
            const float4 w1 = *(const float4*)&w_lds[k * 128 + c0 + 4];
            acc[0][0] += a0 * w0.x; acc[0][1] += a0 * w0.y;
            acc[0][2] += a0 * w0.z; acc[0][3] += a0 * w0.w;
            acc[0][4] += a0 * w1.x; acc[0][5] += a0 * w1.y;
            acc[0][6] += a0 * w1.z; acc[0][7] += a0 * w1.w;
            acc[1][0] += a1 * w0.x; acc[1][1] += a1 * w0.y;
            acc[1][2] += a1 * w0.z; acc[1][3] += a1 * w0.w;
            acc[1][4] += a1 * w1.x; acc[1][5] += a1 * w1.y;
            acc[1][6] += a1 * w1.z; acc[1][7] += a1 * w1.w;
        }
    }

#pragma unroll
    for (int r = 0; r < 2; r++) {
        long row = rowBase + r0 + r;
        float vals[8];
#pragma unroll
        for (int j = 0; j < 8; j++) vals[j] = acc[r][j] + bias[c0 + j];
        if (MODE == 1) {
            const float* dp = Dx + (long)sdst[row] * 128 + c0;
            const float* ep = Ex + (long)ssrc[row] * 128 + c0;
#pragma unroll
            for (int j = 0; j < 8; j++) vals[j] += dp[j] + ep[j];
        }
        float4* op = (float4*)(Cout + row * 128 + c0);
        op[0] = make_float4(vals[0], vals[1], vals[2], vals[3]);
        op[1] = make_float4(vals[4], vals[5], vals[6], vals[7]);
    }
}

// ---------------------------------------------------------------------------
// BN batch stats: partial sums/sumsq per channel
// ---------------------------------------------------------------------------
__global__ __launch_bounds__(256) void bn_stats_kernel(const float* __restrict__ v, long M,
                                                       float* __restrict__ partial) {
    __shared__ float lds[256];
    int tid = threadIdx.x;
    int c = tid & 127, half = tid >> 7;
    float sum = 0.f, sq = 0.f;
    for (long r = (long)blockIdx.x * 2 + half; r < M; r += (long)gridDim.x * 2) {
        float x = v[r * 128 + c];
        sum += x; sq += x * x;
    }
    lds[tid] = sum;
    __syncthreads();
    if (half == 0) sum += lds[tid + 128];
    __syncthreads();
    lds[tid] = sq;
    __syncthreads();
    if (half == 0) {
        sq += lds[tid + 128];
        partial[(long)blockIdx.x * 256 + c] = sum;
        partial[(long)blockIdx.x * 256 + 128 + c] = sq;
    }
}

__global__ void bn_finalize_kernel(const float* __restrict__ partial, int nblk, float invM,
                                   float* __restrict__ stat) {
    int c = threadIdx.x;  // 128 threads
    float s = 0.f, q = 0.f;
    for (int i = 0; i < nblk; i++) {
        s += partial[i * 256 + c];
        q += partial[i * 256 + 128 + c];
    }
    float mu = s * invM;
    float var = q * invM - mu * mu;
    stat[c] = mu;
    stat[128 + c] = rsqrtf(var + 1e-5f);
}

// io = relu(g*(vin-mu)*rsig + b) + io   (elementwise, float4)
__global__ void bn_apply_res_kernel(const float* __restrict__ vin, const float* __restrict__ stat,
                                    const float* __restrict__ g, const float* __restrict__ b,
                                    float* __restrict__ io, long M4) {
    long idx = (long)blockIdx.x * 256 + threadIdx.x;
    if (idx >= M4) return;
    int c4 = (idx & 31) << 2;
    float4 x = ((const float4*)vin)[idx];
    float4 res = ((float4*)io)[idx];
    float xv[4] = {x.x, x.y, x.z, x.w};
    float rv[4] = {res.x, res.y, res.z, res.w};
    float o[4];
#pragma unroll
    for (int t = 0; t < 4; t++) {
        int c = c4 + t;
        float y = g[c] * (xv[t] - stat[c]) * stat[128 + c] + b[c];
        o[t] = fmaxf(y, 0.f) + rv[t];
    }
    ((float4*)io)[idx] = make_float4(o[0], o[1], o[2], o[3]);
}

// ---------------------------------------------------------------------------
// aggregation: h_new = Ax + (sum sigma*Bx[src]) / (sum sigma + 1e-6), CSR by dst
// ---------------------------------------------------------------------------
__global__ __launch_bounds__(128) void aggregate_kernel(
    const float* __restrict__ eij, const float* __restrict__ Bx, const float* __restrict__ Ax,
    const int* __restrict__ row_ptr, const int* __restrict__ ssrc, float* __restrict__ hnew) {
    int i = blockIdx.x, c = threadIdx.x;
    int s0 = row_ptr[i], s1 = row_ptr[i + 1];
    float num = 0.f, den = 0.f;
    for (int j = s0; j < s1; j++) {
        float sig = 1.f / (1.f + __expf(-eij[(long)j * 128 + c]));
        num += sig * Bx[(long)ssrc[j] * 128 + c];
        den += sig;
    }
    long idx = (long)i * 128 + c;
    hnew[idx] = Ax[idx] + num / (den + 1e-6f);
}

// ---------------------------------------------------------------------------
// fused attention per (batch, head): scores+sph-softmax+PV, K/V in LDS
// ---------------------------------------------------------------------------
__global__ __launch_bounds__(256) void attn_kernel(const float* __restrict__ q,
                                                   const float* __restrict__ k,
                                                   const float* __restrict__ v,
                                                   const float* __restrict__ sph,
                                                   float* __restrict__ o) {
    __shared__ float k_lds[128 * 32];
    __shared__ float v_lds[128 * 32];
    int b = blockIdx.x >> 2, hd = blockIdx.x & 3;
    int tid = threadIdx.x;

    for (int i = tid; i < 1024; i += 256) {
        int t = i >> 3, d4 = i & 7;
        long gidx = (long)(b * 128 + t) * 32 + hd * 8 + d4;
        ((float4*)k_lds)[t * 8 + d4] = ((const float4*)k)[gidx];
        ((float4*)v_lds)[t * 8 + d4] = ((const float4*)v)[gidx];
    }
    __syncthreads();

    int s = tid >> 1, t0 = (tid & 1) * 64;
    float4 qreg[8];
    long qbase = (long)(b * 128 + s) * 32 + hd * 8;
#pragma unroll
    for (int j = 0; j < 8; j++) qreg[j] = ((const float4*)q)[qbase + j];
    const float* sphrow = sph + ((long)b * 128 + s) * 128 + t0;
    const float inv_sqrt_dk = 0.17677669529663687f;

    float p[64];
#pragma unroll
    for (int i = 0; i < 64; i++) {
        const float4* kr = (const float4*)&k_lds[(t0 + i) * 32];
        float acc = 0.f;
#pragma unroll
        for (int j = 0; j < 8; j++) {
            float4 kv = kr[j];
            acc += qreg[j].x * kv.x + qreg[j].y * kv.y + qreg[j].z * kv.z + qreg[j].w * kv.w;
        }
        p[i] = acc * inv_sqrt_dk * sphrow[i];
    }
    float m = -1e30f;
#pragma unroll
    for (int i = 0; i < 64; i++) m = fmaxf(m, p[i]);
    m = fmaxf(m, __shfl_xor(m, 1));
    float l = 0.f;
#pragma unroll
    for (int i = 0; i < 64; i++) {
        p[i] = __expf(p[i] - m);
        l += p[i];
    }
    l += __shfl_xor(l, 1);
    float invl = 1.f / l;

    float part[32];
#pragma unroll
    for (int d = 0; d < 32; d++) part[d] = 0.f;
#pragma unroll
    for (int i = 0; i < 64; i++) {
        float pv = p[i] * invl;
        const float4* vr = (const float4*)&v_lds[(t0 + i) * 32];
#pragma unroll
        for (int j = 0; j < 8; j++) {
            float4 vv = vr[j];
            part[4 * j + 0] += pv * vv.x;
            part[4 * j + 1] += pv * vv.y;
            part[4 * j + 2] += pv * vv.z;
            part[4 * j + 3] += pv * vv.w;
        }
    }
    int halfw = tid & 1;
    float outv[16];
#pragma unroll
    for (int d = 0; d < 32; d++) {
        float tot = part[d] + __shfl_xor(part[d], 1);
        if ((d >> 4) == halfw) outv[d & 15] = tot;
    }
    long obase = (long)(b * 128 + s) * 32 + hd * 8 + halfw * 4;
#pragma unroll
    for (int j = 0; j < 4; j++)
        ((float4*)o)[obase + j] = make_float4(outv[4 * j], outv[4 * j + 1], outv[4 * j + 2], outv[4 * j + 3]);
}

// ---------------------------------------------------------------------------
// mean-pool per graph + 3-layer MLP
// ---------------------------------------------------------------------------
__global__ __launch_bounds__(128) void pool_mlp_kernel(
    const float* __restrict__ h, const float* __restrict__ w1, const float* __restrict__ b1,
    const float* __restrict__ w2, const float* __restrict__ b2, const float* __restrict__ w3,
    const float* __restrict__ b3, float* __restrict__ out) {
    __shared__ float g[128], m1[64], m2[32];
    int b = blockIdx.x, tid = threadIdx.x;
    const float* hb = h + (long)b * 128 * 128;
    float s = 0.f;
    for (int r = 0; r < 128; r++) s += hb[r * 128 + tid];
    g[tid] = s * (1.f / 128.f);
    __syncthreads();
    if (tid < 64) {
        float a = b1[tid];
        for (int kk = 0; kk < 128; kk++) a += g[kk] * w1[kk * 64 + tid];
        m1[tid] = fmaxf(a, 0.f);
    }
    __syncthreads();
    if (tid < 32) {
        float a = b2[tid];
        for (int kk = 0; kk < 64; kk++) a += m1[kk] * w2[kk * 32 + tid];
        m2[tid] = fmaxf(a, 0.f);
    }
    __syncthreads();
    if (tid < 10) {
        float a = b3[tid];
        for (int kk = 0; kk < 32; kk++) a += m2[kk] * w3[kk * 10 + tid];
        out[b * 10 + tid] = a;
    }
}

// ---------------------------------------------------------------------------
extern "C" void kernel_launch(void* const* d_in, const int* in_sizes, int n_in,
                              void* d_out, int out_size, void* d_ws, size_t ws_size,
                              hipStream_t stream) {
    (void)in_sizes; (void)n_in; (void)out_size;
    const float* x        = (const float*)d_in[0];
    const float* pe       = (const float*)d_in[1];
    const float* edge_attr= (const float*)d_in[2];
    const float* sph      = (const float*)d_in[3];
    const float* node_w   = (const float*)d_in[4];
    const float* node_b   = (const float*)d_in[5];
    const float* pe_w     = (const float*)d_in[6];
    const float* pe_b     = (const float*)d_in[7];
    const float* conv_Aw  = (const float*)d_in[8];
    const float* conv_Ab  = (const float*)d_in[9];
    const float* conv_Bw  = (const float*)d_in[10];
    const float* conv_Bb  = (const float*)d_in[11];
    const float* conv_Cw  = (const float*)d_in[12];
    const float* conv_Cb  = (const float*)d_in[13];
    const float* conv_Dw  = (const float*)d_in[14];
    const float* conv_Db  = (const float*)d_in[15];
    const float* conv_Ew  = (const float*)d_in[16];
    const float* conv_Eb  = (const float*)d_in[17];
    const float* bnx_g    = (const float*)d_in[18];
    const float* bnx_b    = (const float*)d_in[19];
    const float* bne_g    = (const float*)d_in[20];
    const float* bne_b    = (const float*)d_in[21];
    const float* attn_w   = (const float*)d_in[22];
    const float* attn_b   = (const float*)d_in[23];
    const float* mlp1_w   = (const float*)d_in[24];
    const float* mlp1_b   = (const float*)d_in[25];
    const float* mlp2_w   = (const float*)d_in[26];
    const float* mlp2_b   = (const float*)d_in[27];
    const float* mlp3_w   = (const float*)d_in[28];
    const float* mlp3_b   = (const float*)d_in[29];
    const int*   eidx     = (const int*)d_in[30];
    const int* esrc = eidx;
    const int* edst = eidx + E_E;
    float* out = (float*)d_out;

    // workspace carve (floats first, then ints)
    float* f = (float*)d_ws;
    float* h      = f; f += (long)N_N * HID;
    float* hnew   = f; f += (long)N_N * HID;
    float* Ax     = f; f += (long)N_N * HID;   // q later
    float* Bx     = f; f += (long)N_N * HID;   // k later
    float* Dx     = f; f += (long)N_N * HID;   // v later
    float* Ex     = f; f += (long)N_N * HID;   // o later
    float* e      = f; f += (long)E_E * HID;
    float* eij    = f; f += (long)E_E * HID;
    float* partial= f; f += 512 * 256;
    float* bnxs   = f; f += 256;
    float* bnes   = f; f += 256;
    int* ip = (int*)f;
    int* deg     = ip; ip += N_N;
    int* row_ptr = ip; ip += N_N + 1;
    int* cursor  = ip; ip += N_N;
    int* perm    = ip; ip += E_E;
    int* ssrc    = ip; ip += E_E;
    int* sdst    = ip; ip += E_E;
    size_t need = (size_t)((char*)ip - (char*)d_ws);
    if (ws_size < need) return;  // out -> stays poisoned: signals ws too small

    // ---- build CSR by dst, permute edge features into dst-sorted order ----
    zero_int_kernel<<<(N_N + 255) / 256, 256, 0, stream>>>(deg, N_N);
    hist_kernel<<<E_E / 256, 256, 0, stream>>>(edst, deg);
    scan_kernel<<<1, 1024, 0, stream>>>(deg, row_ptr, cursor);
    scatter_kernel<<<E_E / 256, 256, 0, stream>>>(esrc, edst, cursor, perm, ssrc, sdst);
    permute_kernel<<<E_E * 32 / 256, 256, 0, stream>>>(edge_attr, perm, e);

    embed_kernel<<<N_N * HID / 256, 256, 0, stream>>>(x, pe, node_w, node_b, pe_w, pe_b, h);

    for (int l = 0; l < L_LAYERS; l++) {
        const float* Aw = conv_Aw + l * 16384; const float* Ab = conv_Ab + l * 128;
        const float* Bw = conv_Bw + l * 16384; const float* Bb = conv_Bb + l * 128;
        const float* Cw = conv_Cw + l * 16384; const float* Cb = conv_Cb + l * 128;
        const float* Dw = conv_Dw + l * 16384; const float* Db = conv_Db + l * 128;
        const float* Ew = conv_Ew + l * 16384; const float* Eb = conv_Eb + l * 128;

        gemm128_kernel<0><<<N_N / 32, 256, 0, stream>>>(h, Aw, Ab, Ax, nullptr, nullptr, nullptr, nullptr);
        gemm128_kernel<0><<<N_N / 32, 256, 0, stream>>>(h, Bw, Bb, Bx, nullptr, nullptr, nullptr, nullptr);
        gemm128_kernel<0><<<N_N / 32, 256, 0, stream>>>(h, Dw, Db, Dx, nullptr, nullptr, nullptr, nullptr);
        gemm128_kernel<0><<<N_N / 32, 256, 0, stream>>>(h, Ew, Eb, Ex, nullptr, nullptr, nullptr, nullptr);
        // e_ij = e@Cw + Cb + Dx[dst] + Ex[src]
        gemm128_kernel<1><<<E_E / 32, 256, 0, stream>>>(e, Cw, Cb, eij, Dx, Ex, sdst, ssrc);

        bn_stats_kernel<<<512, 256, 0, stream>>>(eij, (long)E_E, partial);
        bn_finalize_kernel<<<1, 128, 0, stream>>>(partial, 512, 1.f / E_E, bnes);

        aggregate_kernel<<<N_N, 128, 0, stream>>>(eij, Bx, Ax, row_ptr, ssrc, hnew);

        bn_stats_kernel<<<128, 256, 0, stream>>>(hnew, (long)N_N, partial);
        bn_finalize_kernel<<<1, 128, 0, stream>>>(partial, 128, 1.f / N_N, bnxs);

        bn_apply_res_kernel<<<N_N * 32 / 256, 256, 0, stream>>>(hnew, bnxs, bnx_g + l * 128, bnx_b + l * 128, h, (long)N_N * 32);
        bn_apply_res_kernel<<<E_E * 32 / 256, 256, 0, stream>>>(eij, bnes, bne_g + l * 128, bne_b + l * 128, e, (long)E_E * 32);

        // attention: q=Ax, k=Bx, v=Dx, o=Ex
        gemm128_kernel<0><<<N_N / 32, 256, 0, stream>>>(h, attn_w, attn_b, Ax, nullptr, nullptr, nullptr, nullptr);
        gemm128_kernel<0><<<N_N / 32, 256, 0, stream>>>(h, attn_w + 16384, attn_b + 128, Bx, nullptr, nullptr, nullptr, nullptr);
        gemm128_kernel<0><<<N_N / 32, 256, 0, stream>>>(h, attn_w + 32768, attn_b + 256, Dx, nullptr, nullptr, nullptr, nullptr);
        attn_kernel<<<B_G * HEADS, 256, 0, stream>>>(Ax, Bx, Dx, sph, Ex);
        // h replaced by projection of o
        gemm128_kernel<0><<<N_N / 32, 256, 0, stream>>>(Ex, attn_w + 49152, attn_b + 384, h, nullptr, nullptr, nullptr, nullptr);
    }

    pool_mlp_kernel<<<B_G, 128, 0, stream>>>(h, mlp1_w, mlp1_b, mlp2_w, mlp2_b, mlp3_w, mlp3_b, out);
}

// Round 2
// 2367.590 us; speedup vs baseline: 1.4195x; 1.4195x over previous
//
#include <hip/hip_runtime.h>
#include <math.h>

// Problem constants
#define L_LAYERS 4
#define B_G 128
#define S_G 128
#define N_N 16384      // B*S
#define E_E 262144
#define IN_F 64
#define HID 128
#define PE_F 16
#define HEADS 4
#define DK 32
#define OUT_F 10

// ---------------------------------------------------------------------------
// init: CSR-by-dst build
// ---------------------------------------------------------------------------
__global__ void zero_int_kernel(int* __restrict__ p, int n) {
    int i = blockIdx.x * 256 + threadIdx.x;
    if (i < n) p[i] = 0;
}

__global__ void hist_kernel(const int* __restrict__ dst, int* __restrict__ deg) {
    int e = blockIdx.x * 256 + threadIdx.x;
    if (e < E_E) atomicAdd(&deg[dst[e]], 1);
}

__global__ __launch_bounds__(1024) void scan_kernel(const int* __restrict__ deg,
                                                    int* __restrict__ row_ptr,
                                                    int* __restrict__ cursor) {
    __shared__ int lds[1024];
    int tid = threadIdx.x;
    int base = tid * 16;
    int d[16];
    int s = 0;
#pragma unroll
    for (int i = 0; i < 16; i++) { d[i] = deg[base + i]; s += d[i]; }
    lds[tid] = s;
    __syncthreads();
    for (int off = 1; off < 1024; off <<= 1) {
        int v = (tid >= off) ? lds[tid - off] : 0;
        __syncthreads();
        lds[tid] += v;
        __syncthreads();
    }
    int run = lds[tid] - s;  // exclusive prefix
#pragma unroll
    for (int i = 0; i < 16; i++) {
        row_ptr[base + i] = run;
        cursor[base + i] = run;
        run += d[i];
    }
    if (tid == 1023) row_ptr[N_N] = run;
}

__global__ void scatter_kernel(const int* __restrict__ src, const int* __restrict__ dst,
                               int* __restrict__ cursor, int* __restrict__ perm,
                               int* __restrict__ ssrc, int* __restrict__ sdst) {
    int e = blockIdx.x * 256 + threadIdx.x;
    if (e >= E_E) return;
    int dd = dst[e];
    int pos = atomicAdd(&cursor[dd], 1);
    perm[pos] = e;
    ssrc[pos] = src[e];
    sdst[pos] = dd;
}

// ---------------------------------------------------------------------------
// embed: h = [x@node_w+node_b | pe@pe_w+pe_b]
// ---------------------------------------------------------------------------
__global__ void embed_kernel(const float* __restrict__ x, const float* __restrict__ pe,
                             const float* __restrict__ node_w, const float* __restrict__ node_b,
                             const float* __restrict__ pe_w, const float* __restrict__ pe_b,
                             float* __restrict__ h) {
    int idx = blockIdx.x * 256 + threadIdx.x;
    if (idx >= N_N * HID) return;
    int i = idx >> 7, c = idx & 127;
    float acc;
    if (c < 112) {
        acc = node_b[c];
        const float* xr = x + (long)i * IN_F;
        for (int k = 0; k < IN_F; k++) acc += xr[k] * node_w[k * 112 + c];
    } else {
        int cc = c - 112;
        acc = pe_b[cc];
        const float* pr = pe + (long)i * PE_F;
        for (int k = 0; k < PE_F; k++) acc += pr[k] * pe_w[k * PE_F + cc];
    }
    h[idx] = acc;
}

// ---------------------------------------------------------------------------
// GEMM v2: C[M][128] = A[M][128] @ W[128][128] + bias
// 256 thr, 64 rows/block, thread tile 4 rows x 8 cols (cols c0..c0+3, c0+64..c0+67).
// A in LDS k-interleaved [kblk][row*4+kk] (stride 260) -> aligned conflict-free
// ds_read_b128; W quarters (16KB) -> total LDS 49.7KB, 3 blocks/CU.
// MODE 1 (edge): A-rows gathered via permRows (layer 0), epilogue adds
// Dx[sdst]+Ex[ssrc], and BN batch-stats (sum, sumsq per channel) are reduced
// in-block and atomically accumulated into stats_acc[256].
// ---------------------------------------------------------------------------
template <int MODE>
__global__ __launch_bounds__(256) void gemm128v2_kernel(
    const float* __restrict__ A, const float* __restrict__ W, const float* __restrict__ bias,
    float* __restrict__ Cout, const float* __restrict__ Dx, const float* __restrict__ Ex,
    const int* __restrict__ sdst, const int* __restrict__ ssrc,
    const int* __restrict__ permRows, float* __restrict__ stats_acc) {
    __shared__ float w_lds[32 * 128];    // 16KB: one k-quarter of W
    __shared__ float a_lds[32 * 260];    // 33.3KB: 32 kblks x (64 rows * 4 k + pad)
    int tid = threadIdx.x;
    long rowBase = (long)blockIdx.x * 64;

    // stage A: 64 rows x 128 cols, k-interleaved
    for (int i = tid; i < 2048; i += 256) {
        int r = i >> 5, c4 = i & 31;
        long grow = rowBase + r;
        if (MODE == 1 && permRows) grow = permRows[grow];
        float4 v = ((const float4*)(A + grow * 128))[c4];
        *(float4*)&a_lds[c4 * 260 + r * 4] = v;
    }

    int cg = tid & 15, rp = tid >> 4;   // rp in [0,16)
    int c0 = cg << 2;
    float acc[4][8];
#pragma unroll
    for (int j = 0; j < 4; j++)
#pragma unroll
        for (int t = 0; t < 8; t++) acc[j][t] = 0.f;

    for (int kp = 0; kp < 4; kp++) {
        if (kp) __syncthreads();
        const float4* Wv = (const float4*)(W + kp * 32 * 128);
        for (int i = tid; i < 1024; i += 256) ((float4*)w_lds)[i] = Wv[i];
        __syncthreads();
#pragma unroll
        for (int kb = 0; kb < 8; kb++) {
            int kblk = kp * 8 + kb;
            float ar[4][4];
#pragma unroll
            for (int j = 0; j < 4; j++) {
                float4 a4 = *(const float4*)&a_lds[kblk * 260 + (rp + 16 * j) * 4];
                ar[j][0] = a4.x; ar[j][1] = a4.y; ar[j][2] = a4.z; ar[j][3] = a4.w;
            }
#pragma unroll
            for (int kk = 0; kk < 4; kk++) {
                int kl = kb * 4 + kk;
                const float4 w0 = *(const float4*)&w_lds[kl * 128 + c0];
                const float4 w1 = *(const float4*)&w_lds[kl * 128 + c0 + 64];
#pragma unroll
                for (int j = 0; j < 4; j++) {
                    float a = ar[j][kk];
                    acc[j][0] += a * w0.x; acc[j][1] += a * w0.y;
                    acc[j][2] += a * w0.z; acc[j][3] += a * w0.w;
                    acc[j][4] += a * w1.x; acc[j][5] += a * w1.y;
                    acc[j][6] += a * w1.z; acc[j][7] += a * w1.w;
                }
            }
        }
    }

    float colsum[8], colsq[8];
#pragma unroll
    for (int t = 0; t < 8; t++) { colsum[t] = 0.f; colsq[t] = 0.f; }

#pragma unroll
    for (int j = 0; j < 4; j++) {
        long row = rowBase + rp + 16 * j;
        float vals[8];
#pragma unroll
        for (int t = 0; t < 4; t++) {
            vals[t] = acc[j][t] + bias[c0 + t];
            vals[4 + t] = acc[j][4 + t] + bias[c0 + 64 + t];
        }
        if (MODE == 1) {
            const float* dp = Dx + (long)sdst[row] * 128;
            const float* ep = Ex + (long)ssrc[row] * 128;
#pragma unroll
            for (int t = 0; t < 4; t++) {
                vals[t] += dp[c0 + t] + ep[c0 + t];
                vals[4 + t] += dp[c0 + 64 + t] + ep[c0 + 64 + t];
            }
        }
        ((float4*)(Cout + row * 128 + c0))[0] = make_float4(vals[0], vals[1], vals[2], vals[3]);
        ((float4*)(Cout + row * 128 + c0 + 64))[0] = make_float4(vals[4], vals[5], vals[6], vals[7]);
        if (MODE == 1) {
#pragma unroll
            for (int t = 0; t < 8; t++) { colsum[t] += vals[t]; colsq[t] += vals[t] * vals[t]; }
        }
    }

    if (MODE == 1) {
        // block-reduce per-channel stats over the 16 rp groups, then atomics
        float* ssum = a_lds;          // 16*128
        float* ssq = a_lds + 2048;    // 16*128
        __syncthreads();  // done reading a_lds for GEMM
#pragma unroll
        for (int t = 0; t < 4; t++) {
            ssum[rp * 128 + c0 + t] = colsum[t];
            ssum[rp * 128 + c0 + 64 + t] = colsum[4 + t];
            ssq[rp * 128 + c0 + t] = colsq[t];
            ssq[rp * 128 + c0 + 64 + t] = colsq[4 + t];
        }
        __syncthreads();
        for (int off = 8; off; off >>= 1) {
            if (rp < off) {
#pragma unroll
                for (int t = 0; t < 4; t++) {
                    ssum[rp * 128 + c0 + t] += ssum[(rp + off) * 128 + c0 + t];
                    ssum[rp * 128 + c0 + 64 + t] += ssum[(rp + off) * 128 + c0 + 64 + t];
                    ssq[rp * 128 + c0 + t] += ssq[(rp + off) * 128 + c0 + t];
                    ssq[rp * 128 + c0 + 64 + t] += ssq[(rp + off) * 128 + c0 + 64 + t];
                }
            }
            __syncthreads();
        }
        float v = (tid < 128) ? ssum[tid] : ssq[tid - 128];
        atomicAdd(&stats_acc[tid], v);
    }
}

// stats_acc[0..127]=sum, [128..255]=sumsq -> stat[0..127]=mu, [128..255]=rsig
__global__ void ebn_finalize_kernel(const float* __restrict__ acc, float invM,
                                    float* __restrict__ stat) {
    int c = threadIdx.x;  // 128
    float mu = acc[c] * invM;
    float var = acc[128 + c] * invM - mu * mu;
    stat[c] = mu;
    stat[128 + c] = rsqrtf(var + 1e-5f);
}

// ---------------------------------------------------------------------------
// BN batch stats (node path): partial sums/sumsq per channel
// ---------------------------------------------------------------------------
__global__ __launch_bounds__(256) void bn_stats_kernel(const float* __restrict__ v, long M,
                                                       float* __restrict__ partial) {
    __shared__ float lds[256];
    int tid = threadIdx.x;
    int c = tid & 127, half = tid >> 7;
    float sum = 0.f, sq = 0.f;
    for (long r = (long)blockIdx.x * 2 + half; r < M; r += (long)gridDim.x * 2) {
        float x = v[r * 128 + c];
        sum += x; sq += x * x;
    }
    lds[tid] = sum;
    __syncthreads();
    if (half == 0) sum += lds[tid + 128];
    __syncthreads();
    lds[tid] = sq;
    __syncthreads();
    if (half == 0) {
        sq += lds[tid + 128];
        partial[(long)blockIdx.x * 256 + c] = sum;
        partial[(long)blockIdx.x * 256 + 128 + c] = sq;
    }
}

__global__ void bn_finalize_kernel(const float* __restrict__ partial, int nblk, float invM,
                                   float* __restrict__ stat) {
    int c = threadIdx.x;  // 128 threads
    float s = 0.f, q = 0.f;
    for (int i = 0; i < nblk; i++) {
        s += partial[i * 256 + c];
        q += partial[i * 256 + 128 + c];
    }
    float mu = s * invM;
    float var = q * invM - mu * mu;
    stat[c] = mu;
    stat[128 + c] = rsqrtf(var + 1e-5f);
}

// io = relu(g*(vin-mu)*rsig + b) + io   (elementwise, float4)
__global__ void bn_apply_res_kernel(const float* __restrict__ vin, const float* __restrict__ stat,
                                    const float* __restrict__ g, const float* __restrict__ b,
                                    float* __restrict__ io, long M4) {
    long idx = (long)blockIdx.x * 256 + threadIdx.x;
    if (idx >= M4) return;
    int c4 = (idx & 31) << 2;
    float4 x = ((const float4*)vin)[idx];
    float4 res = ((float4*)io)[idx];
    float xv[4] = {x.x, x.y, x.z, x.w};
    float rv[4] = {res.x, res.y, res.z, res.w};
    float o[4];
#pragma unroll
    for (int t = 0; t < 4; t++) {
        int c = c4 + t;
        float y = g[c] * (xv[t] - stat[c]) * stat[128 + c] + b[c];
        o[t] = fmaxf(y, 0.f) + rv[t];
    }
    ((float4*)io)[idx] = make_float4(o[0], o[1], o[2], o[3]);
}

// ---------------------------------------------------------------------------
// fused aggregation + edge BN/relu/residual (single pass over eij, CSR by dst):
//   e[j]    = relu(bn_e(eij[j])) + eold[j]
//   hnew[i] = Ax[i] + sum(sig*Bx[src]) / (sum(sig)+1e-6)
// ---------------------------------------------------------------------------
__global__ __launch_bounds__(128) void agg_bn_kernel(
    const float* __restrict__ eij, const float* __restrict__ Bx, const float* __restrict__ Ax,
    const int* __restrict__ row_ptr, const int* __restrict__ ssrc,
    const float* __restrict__ estat, const float* __restrict__ g, const float* __restrict__ b,
    const float* __restrict__ eold, const int* __restrict__ perm,
    float* __restrict__ e_out, float* __restrict__ hnew) {
    int i = blockIdx.x, c = threadIdx.x;
    int s0 = row_ptr[i], s1 = row_ptr[i + 1];
    float mu = estat[c], rs = estat[128 + c], gg = g[c], bb = b[c];
    float num = 0.f, den = 0.f;
    for (int j = s0; j < s1; j++) {
        float x = eij[(long)j * 128 + c];
        float sig = 1.f / (1.f + __expf(-x));
        num += sig * Bx[(long)ssrc[j] * 128 + c];
        den += sig;
        long er = perm ? (long)perm[j] : (long)j;
        float old = eold[er * 128 + c];
        float y = fmaxf(gg * (x - mu) * rs + bb, 0.f) + old;
        e_out[(long)j * 128 + c] = y;
    }
    long idx = (long)i * 128 + c;
    hnew[idx] = Ax[idx] + num / (den + 1e-6f);
}

// ---------------------------------------------------------------------------
// fused attention per (batch, head): scores+sph-softmax+PV, K/V in LDS
// ---------------------------------------------------------------------------
__global__ __launch_bounds__(256) void attn_kernel(const float* __restrict__ q,
                                                   const float* __restrict__ k,
                                                   const float* __restrict__ v,
                                                   const float* __restrict__ sph,
                                                   float* __restrict__ o) {
    __shared__ float k_lds[128 * 32];
    __shared__ float v_lds[128 * 32];
    int b = blockIdx.x >> 2, hd = blockIdx.x & 3;
    int tid = threadIdx.x;

    for (int i = tid; i < 1024; i += 256) {
        int t = i >> 3, d4 = i & 7;
        long gidx = (long)(b * 128 + t) * 32 + hd * 8 + d4;
        ((float4*)k_lds)[t * 8 + d4] = ((const float4*)k)[gidx];
        ((float4*)v_lds)[t * 8 + d4] = ((const float4*)v)[gidx];
    }
    __syncthreads();

    int s = tid >> 1, t0 = (tid & 1) * 64;
    float4 qreg[8];
    long qbase = (long)(b * 128 + s) * 32 + hd * 8;
#pragma unroll
    for (int j = 0; j < 8; j++) qreg[j] = ((const float4*)q)[qbase + j];
    const float* sphrow = sph + ((long)b * 128 + s) * 128 + t0;
    const float inv_sqrt_dk = 0.17677669529663687f;

    float p[64];
#pragma unroll
    for (int i = 0; i < 64; i++) {
        const float4* kr = (const float4*)&k_lds[(t0 + i) * 32];
        float acc = 0.f;
#pragma unroll
        for (int j = 0; j < 8; j++) {
            float4 kv = kr[j];
            acc += qreg[j].x * kv.x + qreg[j].y * kv.y + qreg[j].z * kv.z + qreg[j].w * kv.w;
        }
        p[i] = acc * inv_sqrt_dk * sphrow[i];
    }
    float m = -1e30f;
#pragma unroll
    for (int i = 0; i < 64; i++) m = fmaxf(m, p[i]);
    m = fmaxf(m, __shfl_xor(m, 1));
    float l = 0.f;
#pragma unroll
    for (int i = 0; i < 64; i++) {
        p[i] = __expf(p[i] - m);
        l += p[i];
    }
    l += __shfl_xor(l, 1);
    float invl = 1.f / l;

    float part[32];
#pragma unroll
    for (int d = 0; d < 32; d++) part[d] = 0.f;
#pragma unroll
    for (int i = 0; i < 64; i++) {
        float pv = p[i] * invl;
        const float4* vr = (const float4*)&v_lds[(t0 + i) * 32];
#pragma unroll
        for (int j = 0; j < 8; j++) {
            float4 vv = vr[j];
            part[4 * j + 0] += pv * vv.x;
            part[4 * j + 1] += pv * vv.y;
            part[4 * j + 2] += pv * vv.z;
            part[4 * j + 3] += pv * vv.w;
        }
    }
    int halfw = tid & 1;
    float outv[16];
#pragma unroll
    for (int d = 0; d < 32; d++) {
        float tot = part[d] + __shfl_xor(part[d], 1);
        if ((d >> 4) == halfw) outv[d & 15] = tot;
    }
    long obase = (long)(b * 128 + s) * 32 + hd * 8 + halfw * 4;
#pragma unroll
    for (int j = 0; j < 4; j++)
        ((float4*)o)[obase + j] = make_float4(outv[4 * j], outv[4 * j + 1], outv[4 * j + 2], outv[4 * j + 3]);
}

// ---------------------------------------------------------------------------
// mean-pool per graph + 3-layer MLP
// ---------------------------------------------------------------------------
__global__ __launch_bounds__(128) void pool_mlp_kernel(
    const float* __restrict__ h, const float* __restrict__ w1, const float* __restrict__ b1,
    const float* __restrict__ w2, const float* __restrict__ b2, const float* __restrict__ w3,
    const float* __restrict__ b3, float* __restrict__ out) {
    __shared__ float g[128], m1[64], m2[32];
    int b = blockIdx.x, tid = threadIdx.x;
    const float* hb = h + (long)b * 128 * 128;
    float s = 0.f;
    for (int r = 0; r < 128; r++) s += hb[r * 128 + tid];
    g[tid] = s * (1.f / 128.f);
    __syncthreads();
    if (tid < 64) {
        float a = b1[tid];
        for (int kk = 0; kk < 128; kk++) a += g[kk] * w1[kk * 64 + tid];
        m1[tid] = fmaxf(a, 0.f);
    }
    __syncthreads();
    if (tid < 32) {
        float a = b2[tid];
        for (int kk = 0; kk < 64; kk++) a += m1[kk] * w2[kk * 32 + tid];
        m2[tid] = fmaxf(a, 0.f);
    }
    __syncthreads();
    if (tid < 10) {
        float a = b3[tid];
        for (int kk = 0; kk < 32; kk++) a += m2[kk] * w3[kk * 10 + tid];
        out[b * 10 + tid] = a;
    }
}

// ---------------------------------------------------------------------------
extern "C" void kernel_launch(void* const* d_in, const int* in_sizes, int n_in,
                              void* d_out, int out_size, void* d_ws, size_t ws_size,
                              hipStream_t stream) {
    (void)in_sizes; (void)n_in; (void)out_size;
    const float* x        = (const float*)d_in[0];
    const float* pe       = (const float*)d_in[1];
    const float* edge_attr= (const float*)d_in[2];
    const float* sph      = (const float*)d_in[3];
    const float* node_w   = (const float*)d_in[4];
    const float* node_b   = (const float*)d_in[5];
    const float* pe_w     = (const float*)d_in[6];
    const float* pe_b     = (const float*)d_in[7];
    const float* conv_Aw  = (const float*)d_in[8];
    const float* conv_Ab  = (const float*)d_in[9];
    const float* conv_Bw  = (const float*)d_in[10];
    const float* conv_Bb  = (const float*)d_in[11];
    const float* conv_Cw  = (const float*)d_in[12];
    const float* conv_Cb  = (const float*)d_in[13];
    const float* conv_Dw  = (const float*)d_in[14];
    const float* conv_Db  = (const float*)d_in[15];
    const float* conv_Ew  = (const float*)d_in[16];
    const float* conv_Eb  = (const float*)d_in[17];
    const float* bnx_g    = (const float*)d_in[18];
    const float* bnx_b    = (const float*)d_in[19];
    const float* bne_g    = (const float*)d_in[20];
    const float* bne_b    = (const float*)d_in[21];
    const float* attn_w   = (const float*)d_in[22];
    const float* attn_b   = (const float*)d_in[23];
    const float* mlp1_w   = (const float*)d_in[24];
    const float* mlp1_b   = (const float*)d_in[25];
    const float* mlp2_w   = (const float*)d_in[26];
    const float* mlp2_b   = (const float*)d_in[27];
    const float* mlp3_w   = (const float*)d_in[28];
    const float* mlp3_b   = (const float*)d_in[29];
    const int*   eidx     = (const int*)d_in[30];
    const int* esrc = eidx;
    const int* edst = eidx + E_E;
    float* out = (float*)d_out;

    // workspace carve (floats first, then ints)
    float* f = (float*)d_ws;
    float* h      = f; f += (long)N_N * HID;
    float* hnew   = f; f += (long)N_N * HID;
    float* Ax     = f; f += (long)N_N * HID;   // q later
    float* Bx     = f; f += (long)N_N * HID;   // k later
    float* Dx     = f; f += (long)N_N * HID;   // v later
    float* Ex     = f; f += (long)N_N * HID;   // o later
    float* e      = f; f += (long)E_E * HID;
    float* eij    = f; f += (long)E_E * HID;
    float* partial= f; f += 512 * 256;
    float* bnxs   = f; f += 256;
    float* bnes   = f; f += 256;
    float* ebn_acc= f; f += 256;
    int* ip = (int*)f;
    int* deg     = ip; ip += N_N;
    int* row_ptr = ip; ip += N_N + 1;
    int* cursor  = ip; ip += N_N;
    int* perm    = ip; ip += E_E;
    int* ssrc    = ip; ip += E_E;
    int* sdst    = ip; ip += E_E;
    size_t need = (size_t)((char*)ip - (char*)d_ws);
    if (ws_size < need) return;  // out stays poisoned: signals ws too small

    // ---- build CSR by dst (edge features gathered on the fly via perm) ----
    zero_int_kernel<<<(N_N + 255) / 256, 256, 0, stream>>>(deg, N_N);
    hist_kernel<<<E_E / 256, 256, 0, stream>>>(edst, deg);
    scan_kernel<<<1, 1024, 0, stream>>>(deg, row_ptr, cursor);
    scatter_kernel<<<E_E / 256, 256, 0, stream>>>(esrc, edst, cursor, perm, ssrc, sdst);

    embed_kernel<<<N_N * HID / 256, 256, 0, stream>>>(x, pe, node_w, node_b, pe_w, pe_b, h);

    for (int l = 0; l < L_LAYERS; l++) {
        const float* Aw = conv_Aw + l * 16384; const float* Ab = conv_Ab + l * 128;
        const float* Bw = conv_Bw + l * 16384; const float* Bb = conv_Bb + l * 128;
        const float* Cw = conv_Cw + l * 16384; const float* Cb = conv_Cb + l * 128;
        const float* Dw = conv_Dw + l * 16384; const float* Db = conv_Db + l * 128;
        const float* Ew = conv_Ew + l * 16384; const float* Eb = conv_Eb + l * 128;

        zero_int_kernel<<<1, 256, 0, stream>>>((int*)ebn_acc, 256);

        gemm128v2_kernel<0><<<N_N / 64, 256, 0, stream>>>(h, Aw, Ab, Ax, nullptr, nullptr, nullptr, nullptr, nullptr, nullptr);
        gemm128v2_kernel<0><<<N_N / 64, 256, 0, stream>>>(h, Bw, Bb, Bx, nullptr, nullptr, nullptr, nullptr, nullptr, nullptr);
        gemm128v2_kernel<0><<<N_N / 64, 256, 0, stream>>>(h, Dw, Db, Dx, nullptr, nullptr, nullptr, nullptr, nullptr, nullptr);
        gemm128v2_kernel<0><<<N_N / 64, 256, 0, stream>>>(h, Ew, Eb, Ex, nullptr, nullptr, nullptr, nullptr, nullptr, nullptr);
        // e_ij = e@Cw + Cb + Dx[dst] + Ex[src]; fused BN stats into ebn_acc
        const float* Asrc = (l == 0) ? edge_attr : e;
        const int* permA = (l == 0) ? perm : nullptr;
        gemm128v2_kernel<1><<<E_E / 64, 256, 0, stream>>>(Asrc, Cw, Cb, eij, Dx, Ex, sdst, ssrc, permA, ebn_acc);

        ebn_finalize_kernel<<<1, 128, 0, stream>>>(ebn_acc, 1.f / E_E, bnes);

        // fused: aggregation (hnew) + edge BN/relu/residual (e update), one eij pass
        const float* eoldSrc = (l == 0) ? edge_attr : e;
        const int* permE = (l == 0) ? perm : nullptr;
        agg_bn_kernel<<<N_N, 128, 0, stream>>>(eij, Bx, Ax, row_ptr, ssrc, bnes,
                                               bne_g + l * 128, bne_b + l * 128,
                                               eoldSrc, permE, e, hnew);

        bn_stats_kernel<<<128, 256, 0, stream>>>(hnew, (long)N_N, partial);
        bn_finalize_kernel<<<1, 128, 0, stream>>>(partial, 128, 1.f / N_N, bnxs);
        bn_apply_res_kernel<<<N_N * 32 / 256, 256, 0, stream>>>(hnew, bnxs, bnx_g + l * 128, bnx_b + l * 128, h, (long)N_N * 32);

        // attention: q=Ax, k=Bx, v=Dx, o=Ex
        gemm128v2_kernel<0><<<N_N / 64, 256, 0, stream>>>(h, attn_w, attn_b, Ax, nullptr, nullptr, nullptr, nullptr, nullptr, nullptr);
        gemm128v2_kernel<0><<<N_N / 64, 256, 0, stream>>>(h, attn_w + 16384, attn_b + 128, Bx, nullptr, nullptr, nullptr, nullptr, nullptr, nullptr);
        gemm128v2_kernel<0><<<N_N / 64, 256, 0, stream>>>(h, attn_w + 32768, attn_b + 256, Dx, nullptr, nullptr, nullptr, nullptr, nullptr, nullptr);
        attn_kernel<<<B_G * HEADS, 256, 0, stream>>>(Ax, Bx, Dx, sph, Ex);
        gemm128v2_kernel<0><<<N_N / 64, 256, 0, stream>>>(Ex, attn_w + 49152, attn_b + 384, h, nullptr, nullptr, nullptr, nullptr, nullptr, nullptr);
    }

    pool_mlp_kernel<<<B_G, 128, 0, stream>>>(h, mlp1_w, mlp1_b, mlp2_w, mlp2_b, mlp3_w, mlp3_b, out);
}

// Round 3
// 1861.978 us; speedup vs baseline: 1.8049x; 1.2715x over previous
//
#include <hip/hip_runtime.h>
#include <math.h>

// Problem constants
#define L_LAYERS 4
#define B_G 128
#define S_G 128
#define N_N 16384      // B*S
#define E_E 262144
#define IN_F 64
#define HID 128
#define PE_F 16
#define HEADS 4
#define DK 32
#define OUT_F 10

typedef __bf16 bf16x8 __attribute__((ext_vector_type(8)));
typedef float f32x4 __attribute__((ext_vector_type(4)));

struct Sel4 { float* o[4]; const float* b[4]; int slot[4]; };
struct WSrc24 { const float* w[24]; };

// ---------------------------------------------------------------------------
// init: CSR-by-dst build
// ---------------------------------------------------------------------------
__global__ void zero_int_kernel(int* __restrict__ p, int n) {
    int i = blockIdx.x * 256 + threadIdx.x;
    if (i < n) p[i] = 0;
}

__global__ void hist_kernel(const int* __restrict__ dst, int* __restrict__ deg) {
    int e = blockIdx.x * 256 + threadIdx.x;
    if (e < E_E) atomicAdd(&deg[dst[e]], 1);
}

__global__ __launch_bounds__(1024) void scan_kernel(const int* __restrict__ deg,
                                                    int* __restrict__ row_ptr,
                                                    int* __restrict__ cursor) {
    __shared__ int lds[1024];
    int tid = threadIdx.x;
    int base = tid * 16;
    int d[16];
    int s = 0;
#pragma unroll
    for (int i = 0; i < 16; i++) { d[i] = deg[base + i]; s += d[i]; }
    lds[tid] = s;
    __syncthreads();
    for (int off = 1; off < 1024; off <<= 1) {
        int v = (tid >= off) ? lds[tid - off] : 0;
        __syncthreads();
        lds[tid] += v;
        __syncthreads();
    }
    int run = lds[tid] - s;  // exclusive prefix
#pragma unroll
    for (int i = 0; i < 16; i++) {
        row_ptr[base + i] = run;
        cursor[base + i] = run;
        run += d[i];
    }
    if (tid == 1023) row_ptr[N_N] = run;
}

__global__ void scatter_kernel(const int* __restrict__ src, const int* __restrict__ dst,
                               int* __restrict__ cursor, int* __restrict__ perm,
                               int* __restrict__ ssrc, int* __restrict__ sdst) {
    int e = blockIdx.x * 256 + threadIdx.x;
    if (e >= E_E) return;
    int dd = dst[e];
    int pos = atomicAdd(&cursor[dd], 1);
    perm[pos] = e;
    ssrc[pos] = src[e];
    sdst[pos] = dd;
}

// ---------------------------------------------------------------------------
// weight prepack: fp32 W[k][n] (128x128) -> bf16 hi/lo in MFMA B-frag order.
// packed index p: j=p&7, lane=(p>>3)&63, kc=(p>>9)&3, nt=p>>11
//   k = kc*32 + (lane>>4)*8 + j ; n = nt*16 + (lane&15)
// ---------------------------------------------------------------------------
__global__ __launch_bounds__(256) void pack_w_kernel(WSrc24 ws, __bf16* __restrict__ Whi,
                                                     __bf16* __restrict__ Wlo) {
    int m = blockIdx.x;
    const float* W = ws.w[m];
    int tid = threadIdx.x;
    for (int i = 0; i < 64; i++) {
        int p = i * 256 + tid;
        int j = p & 7, lane = (p >> 3) & 63, kc = (p >> 9) & 3, nt = p >> 11;
        int k = kc * 32 + (lane >> 4) * 8 + j;
        int n = nt * 16 + (lane & 15);
        float w = W[k * 128 + n];
        __bf16 h = (__bf16)w;
        Whi[(long)m * 16384 + p] = h;
        Wlo[(long)m * 16384 + p] = (__bf16)(w - (float)h);
    }
}

// ---------------------------------------------------------------------------
// embed: h = [x@node_w+node_b | pe@pe_w+pe_b]
// ---------------------------------------------------------------------------
__global__ void embed_kernel(const float* __restrict__ x, const float* __restrict__ pe,
                             const float* __restrict__ node_w, const float* __restrict__ node_b,
                             const float* __restrict__ pe_w, const float* __restrict__ pe_b,
                             float* __restrict__ h) {
    int idx = blockIdx.x * 256 + threadIdx.x;
    if (idx >= N_N * HID) return;
    int i = idx >> 7, c = idx & 127;
    float acc;
    if (c < 112) {
        acc = node_b[c];
        const float* xr = x + (long)i * IN_F;
        for (int k = 0; k < IN_F; k++) acc += xr[k] * node_w[k * 112 + c];
    } else {
        int cc = c - 112;
        acc = pe_b[cc];
        const float* pr = pe + (long)i * PE_F;
        for (int k = 0; k < PE_F; k++) acc += pr[k] * pe_w[k * PE_F + cc];
    }
    h[idx] = acc;
}

// ---------------------------------------------------------------------------
// MFMA GEMM: C[M][128] = A[M][128] @ W + bias, bf16x3 split (hi/lo), fp32 acc.
// Block = 256 thr = 4 waves, 64 rows/block; wave owns 16 rows x 128 cols
// (8 tiles of 16x16, K in 4 chunks of 32). No LDS staging, no barrier in
// the main loop: A global->reg (+cvt), B-frags straight from packed global.
// blockIdx.y selects matrix/out/bias (batched node GEMMs).
// MODE 1 (edge): A rows via perm (layer 0), epilogue += Dx[sdst]+Ex[ssrc],
// BN stats reduced (shfl -> LDS -> 256 atomics/block) into stats_acc[256].
// ---------------------------------------------------------------------------
template <int MODE>
__global__ __launch_bounds__(256) void mfma_gemm_kernel(
    const float* __restrict__ A, const int* __restrict__ perm,
    const __bf16* __restrict__ Whi, const __bf16* __restrict__ Wlo, Sel4 sel,
    const float* __restrict__ Dx, const float* __restrict__ Ex,
    const int* __restrict__ sdst, const int* __restrict__ ssrc,
    float* __restrict__ stats_acc) {
    __shared__ float sred[1024];  // MODE1 stats reduce (4 waves x 256)
    int tid = threadIdx.x;
    int lane = tid & 63, wave = tid >> 6;
    int l15 = lane & 15, quad = lane >> 4;
    long rowBase = (long)blockIdx.x * 64 + wave * 16;
    int y = blockIdx.y;
    float* out = sel.o[y];
    const float* bias = sel.b[y];
    const bf16x8* whv = (const bf16x8*)(Whi + (long)sel.slot[y] * 16384);
    const bf16x8* wlv = (const bf16x8*)(Wlo + (long)sel.slot[y] * 16384);

    long arow = rowBase + l15;
    if (MODE == 1 && perm) arow = perm[arow];
    const float* Ap = A + arow * 128 + quad * 8;

    f32x4 acc[8];
#pragma unroll
    for (int t = 0; t < 8; t++) acc[t] = (f32x4){0.f, 0.f, 0.f, 0.f};

#pragma unroll
    for (int kc = 0; kc < 4; kc++) {
        float4 a0 = *(const float4*)(Ap + kc * 32);
        float4 a1 = *(const float4*)(Ap + kc * 32 + 4);
        float f[8] = {a0.x, a0.y, a0.z, a0.w, a1.x, a1.y, a1.z, a1.w};
        bf16x8 ahi, alo;
#pragma unroll
        for (int j = 0; j < 8; j++) {
            __bf16 hh = (__bf16)f[j];
            ahi[j] = hh;
            alo[j] = (__bf16)(f[j] - (float)hh);
        }
#pragma unroll
        for (int nt = 0; nt < 8; nt++) {
            bf16x8 bhi = whv[(nt * 4 + kc) * 64 + lane];
            bf16x8 blo = wlv[(nt * 4 + kc) * 64 + lane];
            acc[nt] = __builtin_amdgcn_mfma_f32_16x16x32_bf16(ahi, blo, acc[nt], 0, 0, 0);
            acc[nt] = __builtin_amdgcn_mfma_f32_16x16x32_bf16(alo, bhi, acc[nt], 0, 0, 0);
            acc[nt] = __builtin_amdgcn_mfma_f32_16x16x32_bf16(ahi, bhi, acc[nt], 0, 0, 0);
        }
    }

    // epilogue. C/D layout: col = lane&15, row = quad*4 + reg  [verified m89/m91]
    int sd[4], ss[4];
    if (MODE == 1) {
#pragma unroll
        for (int r = 0; r < 4; r++) {
            long row = rowBase + quad * 4 + r;
            sd[r] = sdst[row];
            ss[r] = ssrc[row];
        }
    }
    float csum[8], csq[8];
#pragma unroll
    for (int nt = 0; nt < 8; nt++) { csum[nt] = 0.f; csq[nt] = 0.f; }

#pragma unroll
    for (int nt = 0; nt < 8; nt++) {
        int c = nt * 16 + l15;
        float bb = bias[c];
#pragma unroll
        for (int r = 0; r < 4; r++) {
            long row = rowBase + quad * 4 + r;
            float v = acc[nt][r] + bb;
            if (MODE == 1) v += Dx[(long)sd[r] * 128 + c] + Ex[(long)ss[r] * 128 + c];
            out[row * 128 + c] = v;
            if (MODE == 1) { csum[nt] += v; csq[nt] += v * v; }
        }
    }

    if (MODE == 1) {
#pragma unroll
        for (int nt = 0; nt < 8; nt++) {
            float s = csum[nt];
            s += __shfl_xor(s, 16); s += __shfl_xor(s, 32);
            float q = csq[nt];
            q += __shfl_xor(q, 16); q += __shfl_xor(q, 32);
            if (quad == 0) {
                sred[wave * 256 + nt * 16 + l15] = s;
                sred[wave * 256 + 128 + nt * 16 + l15] = q;
            }
        }
        __syncthreads();
        if (tid < 256) {
            float v = sred[tid] + sred[256 + tid] + sred[512 + tid] + sred[768 + tid];
            atomicAdd(&stats_acc[tid], v);
        }
    }
}

// stats_acc[0..127]=sum, [128..255]=sumsq -> stat[0..127]=mu, [128..255]=rsig
__global__ void ebn_finalize_kernel(const float* __restrict__ acc, float invM,
                                    float* __restrict__ stat) {
    int c = threadIdx.x;  // 128
    float mu = acc[c] * invM;
    float var = acc[128 + c] * invM - mu * mu;
    stat[c] = mu;
    stat[128 + c] = rsqrtf(var + 1e-5f);
}

// ---------------------------------------------------------------------------
// BN batch stats (node path): partial sums/sumsq per channel
// ---------------------------------------------------------------------------
__global__ __launch_bounds__(256) void bn_stats_kernel(const float* __restrict__ v, long M,
                                                       float* __restrict__ partial) {
    __shared__ float lds[256];
    int tid = threadIdx.x;
    int c = tid & 127, half = tid >> 7;
    float sum = 0.f, sq = 0.f;
    for (long r = (long)blockIdx.x * 2 + half; r < M; r += (long)gridDim.x * 2) {
        float x = v[r * 128 + c];
        sum += x; sq += x * x;
    }
    lds[tid] = sum;
    __syncthreads();
    if (half == 0) sum += lds[tid + 128];
    __syncthreads();
    lds[tid] = sq;
    __syncthreads();
    if (half == 0) {
        sq += lds[tid + 128];
        partial[(long)blockIdx.x * 256 + c] = sum;
        partial[(long)blockIdx.x * 256 + 128 + c] = sq;
    }
}

__global__ void bn_finalize_kernel(const float* __restrict__ partial, int nblk, float invM,
                                   float* __restrict__ stat) {
    int c = threadIdx.x;  // 128 threads
    float s = 0.f, q = 0.f;
    for (int i = 0; i < nblk; i++) {
        s += partial[i * 256 + c];
        q += partial[i * 256 + 128 + c];
    }
    float mu = s * invM;
    float var = q * invM - mu * mu;
    stat[c] = mu;
    stat[128 + c] = rsqrtf(var + 1e-5f);
}

// io = relu(g*(vin-mu)*rsig + b) + io   (elementwise, float4)
__global__ void bn_apply_res_kernel(const float* __restrict__ vin, const float* __restrict__ stat,
                                    const float* __restrict__ g, const float* __restrict__ b,
                                    float* __restrict__ io, long M4) {
    long idx = (long)blockIdx.x * 256 + threadIdx.x;
    if (idx >= M4) return;
    int c4 = (idx & 31) << 2;
    float4 x = ((const float4*)vin)[idx];
    float4 res = ((float4*)io)[idx];
    float xv[4] = {x.x, x.y, x.z, x.w};
    float rv[4] = {res.x, res.y, res.z, res.w};
    float o[4];
#pragma unroll
    for (int t = 0; t < 4; t++) {
        int c = c4 + t;
        float y = g[c] * (xv[t] - stat[c]) * stat[128 + c] + b[c];
        o[t] = fmaxf(y, 0.f) + rv[t];
    }
    ((float4*)io)[idx] = make_float4(o[0], o[1], o[2], o[3]);
}

// ---------------------------------------------------------------------------
// fused aggregation + edge BN/relu/residual (single pass over eij, CSR by dst)
// ---------------------------------------------------------------------------
__global__ __launch_bounds__(128) void agg_bn_kernel(
    const float* __restrict__ eij, const float* __restrict__ Bx, const float* __restrict__ Ax,
    const int* __restrict__ row_ptr, const int* __restrict__ ssrc,
    const float* __restrict__ estat, const float* __restrict__ g, const float* __restrict__ b,
    const float* __restrict__ eold, const int* __restrict__ perm,
    float* __restrict__ e_out, float* __restrict__ hnew) {
    int i = blockIdx.x, c = threadIdx.x;
    int s0 = row_ptr[i], s1 = row_ptr[i + 1];
    float mu = estat[c], rs = estat[128 + c], gg = g[c], bb = b[c];
    float num = 0.f, den = 0.f;
    for (int j = s0; j < s1; j++) {
        float x = eij[(long)j * 128 + c];
        float sig = 1.f / (1.f + __expf(-x));
        num += sig * Bx[(long)ssrc[j] * 128 + c];
        den += sig;
        long er = perm ? (long)perm[j] : (long)j;
        float old = eold[er * 128 + c];
        float y = fmaxf(gg * (x - mu) * rs + bb, 0.f) + old;
        e_out[(long)j * 128 + c] = y;
    }
    long idx = (long)i * 128 + c;
    hnew[idx] = Ax[idx] + num / (den + 1e-6f);
}

// ---------------------------------------------------------------------------
// fused attention per (batch, head): scores+sph-softmax+PV, K/V in LDS
// ---------------------------------------------------------------------------
__global__ __launch_bounds__(256) void attn_kernel(const float* __restrict__ q,
                                                   const float* __restrict__ k,
                                                   const float* __restrict__ v,
                                                   const float* __restrict__ sph,
                                                   float* __restrict__ o) {
    __shared__ float k_lds[128 * 32];
    __shared__ float v_lds[128 * 32];
    int b = blockIdx.x >> 2, hd = blockIdx.x & 3;
    int tid = threadIdx.x;

    for (int i = tid; i < 1024; i += 256) {
        int t = i >> 3, d4 = i & 7;
        long gidx = (long)(b * 128 + t) * 32 + hd * 8 + d4;
        ((float4*)k_lds)[t * 8 + d4] = ((const float4*)k)[gidx];
        ((float4*)v_lds)[t * 8 + d4] = ((const float4*)v)[gidx];
    }
    __syncthreads();

    int s = tid >> 1, t0 = (tid & 1) * 64;
    float4 qreg[8];
    long qbase = (long)(b * 128 + s) * 32 + hd * 8;
#pragma unroll
    for (int j = 0; j < 8; j++) qreg[j] = ((const float4*)q)[qbase + j];
    const float* sphrow = sph + ((long)b * 128 + s) * 128 + t0;
    const float inv_sqrt_dk = 0.17677669529663687f;

    float p[64];
#pragma unroll
    for (int i = 0; i < 64; i++) {
        const float4* kr = (const float4*)&k_lds[(t0 + i) * 32];
        float acc = 0.f;
#pragma unroll
        for (int j = 0; j < 8; j++) {
            float4 kv = kr[j];
            acc += qreg[j].x * kv.x + qreg[j].y * kv.y + qreg[j].z * kv.z + qreg[j].w * kv.w;
        }
        p[i] = acc * inv_sqrt_dk * sphrow[i];
    }
    float m = -1e30f;
#pragma unroll
    for (int i = 0; i < 64; i++) m = fmaxf(m, p[i]);
    m = fmaxf(m, __shfl_xor(m, 1));
    float l = 0.f;
#pragma unroll
    for (int i = 0; i < 64; i++) {
        p[i] = __expf(p[i] - m);
        l += p[i];
    }
    l += __shfl_xor(l, 1);
    float invl = 1.f / l;

    float part[32];
#pragma unroll
    for (int d = 0; d < 32; d++) part[d] = 0.f;
#pragma unroll
    for (int i = 0; i < 64; i++) {
        float pv = p[i] * invl;
        const float4* vr = (const float4*)&v_lds[(t0 + i) * 32];
#pragma unroll
        for (int j = 0; j < 8; j++) {
            float4 vv = vr[j];
            part[4 * j + 0] += pv * vv.x;
            part[4 * j + 1] += pv * vv.y;
            part[4 * j + 2] += pv * vv.z;
            part[4 * j + 3] += pv * vv.w;
        }
    }
    int halfw = tid & 1;
    float outv[16];
#pragma unroll
    for (int d = 0; d < 32; d++) {
        float tot = part[d] + __shfl_xor(part[d], 1);
        if ((d >> 4) == halfw) outv[d & 15] = tot;
    }
    long obase = (long)(b * 128 + s) * 32 + hd * 8 + halfw * 4;
#pragma unroll
    for (int j = 0; j < 4; j++)
        ((float4*)o)[obase + j] = make_float4(outv[4 * j], outv[4 * j + 1], outv[4 * j + 2], outv[4 * j + 3]);
}

// ---------------------------------------------------------------------------
// mean-pool per graph + 3-layer MLP
// ---------------------------------------------------------------------------
__global__ __launch_bounds__(128) void pool_mlp_kernel(
    const float* __restrict__ h, const float* __restrict__ w1, const float* __restrict__ b1,
    const float* __restrict__ w2, const float* __restrict__ b2, const float* __restrict__ w3,
    const float* __restrict__ b3, float* __restrict__ out) {
    __shared__ float g[128], m1[64], m2[32];
    int b = blockIdx.x, tid = threadIdx.x;
    const float* hb = h + (long)b * 128 * 128;
    float s = 0.f;
    for (int r = 0; r < 128; r++) s += hb[r * 128 + tid];
    g[tid] = s * (1.f / 128.f);
    __syncthreads();
    if (tid < 64) {
        float a = b1[tid];
        for (int kk = 0; kk < 128; kk++) a += g[kk] * w1[kk * 64 + tid];
        m1[tid] = fmaxf(a, 0.f);
    }
    __syncthreads();
    if (tid < 32) {
        float a = b2[tid];
        for (int kk = 0; kk < 64; kk++) a += m1[kk] * w2[kk * 32 + tid];
        m2[tid] = fmaxf(a, 0.f);
    }
    __syncthreads();
    if (tid < 10) {
        float a = b3[tid];
        for (int kk = 0; kk < 32; kk++) a += m2[kk] * w3[kk * 10 + tid];
        out[b * 10 + tid] = a;
    }
}

// ---------------------------------------------------------------------------
extern "C" void kernel_launch(void* const* d_in, const int* in_sizes, int n_in,
                              void* d_out, int out_size, void* d_ws, size_t ws_size,
                              hipStream_t stream) {
    (void)in_sizes; (void)n_in; (void)out_size;
    const float* x        = (const float*)d_in[0];
    const float* pe       = (const float*)d_in[1];
    const float* edge_attr= (const float*)d_in[2];
    const float* sph      = (const float*)d_in[3];
    const float* node_w   = (const float*)d_in[4];
    const float* node_b   = (const float*)d_in[5];
    const float* pe_w     = (const float*)d_in[6];
    const float* pe_b     = (const float*)d_in[7];
    const float* conv_Aw  = (const float*)d_in[8];
    const float* conv_Ab  = (const float*)d_in[9];
    const float* conv_Bw  = (const float*)d_in[10];
    const float* conv_Bb  = (const float*)d_in[11];
    const float* conv_Cw  = (const float*)d_in[12];
    const float* conv_Cb  = (const float*)d_in[13];
    const float* conv_Dw  = (const float*)d_in[14];
    const float* conv_Db  = (const float*)d_in[15];
    const float* conv_Ew  = (const float*)d_in[16];
    const float* conv_Eb  = (const float*)d_in[17];
    const float* bnx_g    = (const float*)d_in[18];
    const float* bnx_b    = (const float*)d_in[19];
    const float* bne_g    = (const float*)d_in[20];
    const float* bne_b    = (const float*)d_in[21];
    const float* attn_w   = (const float*)d_in[22];
    const float* attn_b   = (const float*)d_in[23];
    const float* mlp1_w   = (const float*)d_in[24];
    const float* mlp1_b   = (const float*)d_in[25];
    const float* mlp2_w   = (const float*)d_in[26];
    const float* mlp2_b   = (const float*)d_in[27];
    const float* mlp3_w   = (const float*)d_in[28];
    const float* mlp3_b   = (const float*)d_in[29];
    const int*   eidx     = (const int*)d_in[30];
    const int* esrc = eidx;
    const int* edst = eidx + E_E;
    float* out = (float*)d_out;

    // workspace carve (floats first, then bf16 packs, then ints)
    float* f = (float*)d_ws;
    float* h      = f; f += (long)N_N * HID;
    float* hnew   = f; f += (long)N_N * HID;
    float* Ax     = f; f += (long)N_N * HID;   // q later
    float* Bx     = f; f += (long)N_N * HID;   // k later
    float* Dx     = f; f += (long)N_N * HID;   // v later
    float* Ex     = f; f += (long)N_N * HID;   // o later
    float* e      = f; f += (long)E_E * HID;
    float* eij    = f; f += (long)E_E * HID;
    float* partial= f; f += 512 * 256;
    float* bnxs   = f; f += 256;
    float* bnes   = f; f += 256;
    float* ebn_acc= f; f += 256;
    __bf16* Whi = (__bf16*)f;           // 24 * 16384 bf16
    __bf16* Wlo = Whi + 24 * 16384;
    int* ip = (int*)(Wlo + 24 * 16384);
    int* deg     = ip; ip += N_N;
    int* row_ptr = ip; ip += N_N + 1;
    int* cursor  = ip; ip += N_N;
    int* perm    = ip; ip += E_E;
    int* ssrc    = ip; ip += E_E;
    int* sdst    = ip; ip += E_E;
    size_t need = (size_t)((char*)ip - (char*)d_ws);
    if (ws_size < need) return;  // out stays poisoned: signals ws too small

    // ---- pack all weight matrices (bf16 hi/lo, MFMA B-frag order) ----
    WSrc24 wsrc;
    for (int l = 0; l < L_LAYERS; l++) {
        wsrc.w[l * 5 + 0] = conv_Aw + l * 16384;
        wsrc.w[l * 5 + 1] = conv_Bw + l * 16384;
        wsrc.w[l * 5 + 2] = conv_Cw + l * 16384;
        wsrc.w[l * 5 + 3] = conv_Dw + l * 16384;
        wsrc.w[l * 5 + 4] = conv_Ew + l * 16384;
    }
    for (int m = 0; m < 4; m++) wsrc.w[20 + m] = attn_w + m * 16384;
    pack_w_kernel<<<24, 256, 0, stream>>>(wsrc, Whi, Wlo);

    // ---- build CSR by dst ----
    zero_int_kernel<<<(N_N + 255) / 256, 256, 0, stream>>>(deg, N_N);
    hist_kernel<<<E_E / 256, 256, 0, stream>>>(edst, deg);
    scan_kernel<<<1, 1024, 0, stream>>>(deg, row_ptr, cursor);
    scatter_kernel<<<E_E / 256, 256, 0, stream>>>(esrc, edst, cursor, perm, ssrc, sdst);

    embed_kernel<<<N_N * HID / 256, 256, 0, stream>>>(x, pe, node_w, node_b, pe_w, pe_b, h);

    for (int l = 0; l < L_LAYERS; l++) {
        zero_int_kernel<<<1, 256, 0, stream>>>((int*)ebn_acc, 256);

        // ABDE node GEMMs batched: y selects matrix
        Sel4 selN;
        selN.o[0] = Ax; selN.b[0] = conv_Ab + l * 128; selN.slot[0] = l * 5 + 0;
        selN.o[1] = Bx; selN.b[1] = conv_Bb + l * 128; selN.slot[1] = l * 5 + 1;
        selN.o[2] = Dx; selN.b[2] = conv_Db + l * 128; selN.slot[2] = l * 5 + 3;
        selN.o[3] = Ex; selN.b[3] = conv_Eb + l * 128; selN.slot[3] = l * 5 + 4;
        mfma_gemm_kernel<0><<<dim3(N_N / 64, 4), 256, 0, stream>>>(
            h, nullptr, Whi, Wlo, selN, nullptr, nullptr, nullptr, nullptr, nullptr);

        // edge GEMM: eij = e@Cw + Cb + Dx[dst] + Ex[src], fused BN stats
        const float* Asrc = (l == 0) ? edge_attr : e;
        const int* permA = (l == 0) ? perm : nullptr;
        Sel4 selE;
        selE.o[0] = eij; selE.b[0] = conv_Cb + l * 128; selE.slot[0] = l * 5 + 2;
        selE.o[1] = selE.o[2] = selE.o[3] = eij;
        selE.b[1] = selE.b[2] = selE.b[3] = selE.b[0];
        selE.slot[1] = selE.slot[2] = selE.slot[3] = selE.slot[0];
        mfma_gemm_kernel<1><<<dim3(E_E / 64, 1), 256, 0, stream>>>(
            Asrc, permA, Whi, Wlo, selE, Dx, Ex, sdst, ssrc, ebn_acc);

        ebn_finalize_kernel<<<1, 128, 0, stream>>>(ebn_acc, 1.f / E_E, bnes);

        // fused: aggregation (hnew) + edge BN/relu/residual (e update)
        const float* eoldSrc = (l == 0) ? edge_attr : e;
        const int* permE = (l == 0) ? perm : nullptr;
        agg_bn_kernel<<<N_N, 128, 0, stream>>>(eij, Bx, Ax, row_ptr, ssrc, bnes,
                                               bne_g + l * 128, bne_b + l * 128,
                                               eoldSrc, permE, e, hnew);

        bn_stats_kernel<<<128, 256, 0, stream>>>(hnew, (long)N_N, partial);
        bn_finalize_kernel<<<1, 128, 0, stream>>>(partial, 128, 1.f / N_N, bnxs);
        bn_apply_res_kernel<<<N_N * 32 / 256, 256, 0, stream>>>(
            hnew, bnxs, bnx_g + l * 128, bnx_b + l * 128, h, (long)N_N * 32);

        // qkv batched: q=Ax, k=Bx, v=Dx
        Sel4 selQ;
        selQ.o[0] = Ax; selQ.b[0] = attn_b;       selQ.slot[0] = 20;
        selQ.o[1] = Bx; selQ.b[1] = attn_b + 128; selQ.slot[1] = 21;
        selQ.o[2] = Dx; selQ.b[2] = attn_b + 256; selQ.slot[2] = 22;
        selQ.o[3] = Dx; selQ.b[3] = attn_b + 256; selQ.slot[3] = 22;
        mfma_gemm_kernel<0><<<dim3(N_N / 64, 3), 256, 0, stream>>>(
            h, nullptr, Whi, Wlo, selQ, nullptr, nullptr, nullptr, nullptr, nullptr);

        attn_kernel<<<B_G * HEADS, 256, 0, stream>>>(Ax, Bx, Dx, sph, Ex);

        // output projection: h = o @ Wproj + b
        Sel4 selP;
        selP.o[0] = h; selP.b[0] = attn_b + 384; selP.slot[0] = 23;
        selP.o[1] = selP.o[2] = selP.o[3] = h;
        selP.b[1] = selP.b[2] = selP.b[3] = selP.b[0];
        selP.slot[1] = selP.slot[2] = selP.slot[3] = selP.slot[0];
        mfma_gemm_kernel<0><<<dim3(N_N / 64, 1), 256, 0, stream>>>(
            Ex, nullptr, Whi, Wlo, selP, nullptr, nullptr, nullptr, nullptr, nullptr);
    }

    pool_mlp_kernel<<<B_G, 128, 0, stream>>>(h, mlp1_w, mlp1_b, mlp2_w, mlp2_b, mlp3_w, mlp3_b, out);
}

// Round 4
// 1850.588 us; speedup vs baseline: 1.8160x; 1.0062x over previous
//
#include <hip/hip_runtime.h>
#include <math.h>

// Problem constants
#define L_LAYERS 4
#define B_G 128
#define S_G 128
#define N_N 16384      // B*S
#define E_E 262144
#define IN_F 64
#define HID 128
#define PE_F 16
#define HEADS 4
#define DK 32
#define OUT_F 10

typedef __bf16 bf16x8 __attribute__((ext_vector_type(8)));
typedef float f32x4 __attribute__((ext_vector_type(4)));

struct Sel4 { float* o[4]; const float* b[4]; int slot[4]; };
struct WSrc24 { const float* w[24]; };

// ---------------------------------------------------------------------------
// init: CSR-by-dst build
// ---------------------------------------------------------------------------
__global__ void zero_int_kernel(int* __restrict__ p, int n) {
    int i = blockIdx.x * 256 + threadIdx.x;
    if (i < n) p[i] = 0;
}

__global__ void hist_kernel(const int* __restrict__ dst, int* __restrict__ deg) {
    int e = blockIdx.x * 256 + threadIdx.x;
    if (e < E_E) atomicAdd(&deg[dst[e]], 1);
}

__global__ __launch_bounds__(1024) void scan_kernel(const int* __restrict__ deg,
                                                    int* __restrict__ row_ptr,
                                                    int* __restrict__ cursor) {
    __shared__ int lds[1024];
    int tid = threadIdx.x;
    int base = tid * 16;
    int d[16];
    int s = 0;
#pragma unroll
    for (int i = 0; i < 16; i++) { d[i] = deg[base + i]; s += d[i]; }
    lds[tid] = s;
    __syncthreads();
    for (int off = 1; off < 1024; off <<= 1) {
        int v = (tid >= off) ? lds[tid - off] : 0;
        __syncthreads();
        lds[tid] += v;
        __syncthreads();
    }
    int run = lds[tid] - s;  // exclusive prefix
#pragma unroll
    for (int i = 0; i < 16; i++) {
        row_ptr[base + i] = run;
        cursor[base + i] = run;
        run += d[i];
    }
    if (tid == 1023) row_ptr[N_N] = run;
}

__global__ void scatter_kernel(const int* __restrict__ src, const int* __restrict__ dst,
                               int* __restrict__ cursor, int* __restrict__ perm,
                               int* __restrict__ ssrc, int* __restrict__ sdst) {
    int e = blockIdx.x * 256 + threadIdx.x;
    if (e >= E_E) return;
    int dd = dst[e];
    int pos = atomicAdd(&cursor[dd], 1);
    perm[pos] = e;
    ssrc[pos] = src[e];
    sdst[pos] = dd;
}

// ---------------------------------------------------------------------------
// weight prepack: fp32 W[k][n] (128x128) -> bf16 hi/lo in MFMA B-frag order.
// packed index p: j=p&7, lane=(p>>3)&63, kc=(p>>9)&3, nt=p>>11
//   k = kc*32 + (lane>>4)*8 + j ; n = nt*16 + (lane&15)
// ---------------------------------------------------------------------------
__global__ __launch_bounds__(256) void pack_w_kernel(WSrc24 ws, __bf16* __restrict__ Whi,
                                                     __bf16* __restrict__ Wlo) {
    int m = blockIdx.x;
    const float* W = ws.w[m];
    int tid = threadIdx.x;
    for (int i = 0; i < 64; i++) {
        int p = i * 256 + tid;
        int j = p & 7, lane = (p >> 3) & 63, kc = (p >> 9) & 3, nt = p >> 11;
        int k = kc * 32 + (lane >> 4) * 8 + j;
        int n = nt * 16 + (lane & 15);
        float w = W[k * 128 + n];
        __bf16 h = (__bf16)w;
        Whi[(long)m * 16384 + p] = h;
        Wlo[(long)m * 16384 + p] = (__bf16)(w - (float)h);
    }
}

// ---------------------------------------------------------------------------
// embed: h = [x@node_w+node_b | pe@pe_w+pe_b]
// ---------------------------------------------------------------------------
__global__ void embed_kernel(const float* __restrict__ x, const float* __restrict__ pe,
                             const float* __restrict__ node_w, const float* __restrict__ node_b,
                             const float* __restrict__ pe_w, const float* __restrict__ pe_b,
                             float* __restrict__ h) {
    int idx = blockIdx.x * 256 + threadIdx.x;
    if (idx >= N_N * HID) return;
    int i = idx >> 7, c = idx & 127;
    float acc;
    if (c < 112) {
        acc = node_b[c];
        const float* xr = x + (long)i * IN_F;
        for (int k = 0; k < IN_F; k++) acc += xr[k] * node_w[k * 112 + c];
    } else {
        int cc = c - 112;
        acc = pe_b[cc];
        const float* pr = pe + (long)i * PE_F;
        for (int k = 0; k < PE_F; k++) acc += pr[k] * pe_w[k * PE_F + cc];
    }
    h[idx] = acc;
}

// ---------------------------------------------------------------------------
// Weights-stationary MFMA GEMM, bf16x3 split, fp32 acc.
// Block = 4 waves. Wave w owns cols [32w, 32w+32) = nt tiles {2w, 2w+1} and
// holds all its B-frags (2 nt x 4 kc x hi/lo = 16 x bf16x8 = 64 VGPR) in
// registers for the whole kernel. Grid-stride over 16-row M tiles: per tile
// 8 A-loads : 24 MFMA, no LDS/barriers in the loop.
// blockIdx.y selects matrix/out/bias. MODE 1 (edge): A rows via perm
// (layer 0), epilogue += Dx[sdst]+Ex[ssrc], BN stats accumulated in regs
// across tiles, one LDS reduce + 256 atomics per block at the end.
// ---------------------------------------------------------------------------
template <int MODE>
__global__ __launch_bounds__(256) void mfma_gemm_ws_kernel(
    const float* __restrict__ A, const int* __restrict__ perm,
    const __bf16* __restrict__ Whi, const __bf16* __restrict__ Wlo, Sel4 sel,
    const float* __restrict__ Dx, const float* __restrict__ Ex,
    const int* __restrict__ sdst, const int* __restrict__ ssrc,
    float* __restrict__ stats_acc, int ntiles) {
    __shared__ float sred[256];
    int tid = threadIdx.x;
    int lane = tid & 63, wave = tid >> 6;
    int l15 = lane & 15, quad = lane >> 4;
    int y = blockIdx.y;
    float* out = sel.o[y];
    const float* bias = sel.b[y];
    const bf16x8* whv = (const bf16x8*)(Whi + (long)sel.slot[y] * 16384);
    const bf16x8* wlv = (const bf16x8*)(Wlo + (long)sel.slot[y] * 16384);

    // preload this wave's B-frags into registers (stay resident)
    bf16x8 bh[2][4], bl[2][4];
#pragma unroll
    for (int ntl = 0; ntl < 2; ntl++)
#pragma unroll
        for (int kc = 0; kc < 4; kc++) {
            int fi = ((2 * wave + ntl) * 4 + kc) * 64 + lane;
            bh[ntl][kc] = whv[fi];
            bl[ntl][kc] = wlv[fi];
        }

    // bias for this lane's two columns
    int c0 = (2 * wave) * 16 + l15, c1 = (2 * wave + 1) * 16 + l15;
    float bias0 = bias[c0], bias1 = bias[c1];

    float csum[2] = {0.f, 0.f}, csq[2] = {0.f, 0.f};

    for (int t = blockIdx.x; t < ntiles; t += gridDim.x) {
        long rowA = (long)t * 16 + l15;
        if (MODE == 1 && perm) rowA = perm[rowA];
        const float* Ap = A + rowA * 128 + quad * 8;

        f32x4 acc0 = (f32x4){0.f, 0.f, 0.f, 0.f};
        f32x4 acc1 = (f32x4){0.f, 0.f, 0.f, 0.f};
#pragma unroll
        for (int kc = 0; kc < 4; kc++) {
            float4 a0 = *(const float4*)(Ap + kc * 32);
            float4 a1 = *(const float4*)(Ap + kc * 32 + 4);
            float fv[8] = {a0.x, a0.y, a0.z, a0.w, a1.x, a1.y, a1.z, a1.w};
            bf16x8 ahi, alo;
#pragma unroll
            for (int j = 0; j < 8; j++) {
                __bf16 hh = (__bf16)fv[j];
                ahi[j] = hh;
                alo[j] = (__bf16)(fv[j] - (float)hh);
            }
            acc0 = __builtin_amdgcn_mfma_f32_16x16x32_bf16(ahi, bl[0][kc], acc0, 0, 0, 0);
            acc1 = __builtin_amdgcn_mfma_f32_16x16x32_bf16(ahi, bl[1][kc], acc1, 0, 0, 0);
            acc0 = __builtin_amdgcn_mfma_f32_16x16x32_bf16(alo, bh[0][kc], acc0, 0, 0, 0);
            acc1 = __builtin_amdgcn_mfma_f32_16x16x32_bf16(alo, bh[1][kc], acc1, 0, 0, 0);
            acc0 = __builtin_amdgcn_mfma_f32_16x16x32_bf16(ahi, bh[0][kc], acc0, 0, 0, 0);
            acc1 = __builtin_amdgcn_mfma_f32_16x16x32_bf16(ahi, bh[1][kc], acc1, 0, 0, 0);
        }

        // epilogue. C/D layout: col = lane&15, row = quad*4 + reg
        long rb = (long)t * 16 + quad * 4;
        if (MODE == 1) {
            int sd[4], ss[4];
#pragma unroll
            for (int r = 0; r < 4; r++) { sd[r] = sdst[rb + r]; ss[r] = ssrc[rb + r]; }
#pragma unroll
            for (int r = 0; r < 4; r++) {
                float v0 = acc0[r] + bias0 + Dx[(long)sd[r] * 128 + c0] + Ex[(long)ss[r] * 128 + c0];
                float v1 = acc1[r] + bias1 + Dx[(long)sd[r] * 128 + c1] + Ex[(long)ss[r] * 128 + c1];
                out[(rb + r) * 128 + c0] = v0;
                out[(rb + r) * 128 + c1] = v1;
                csum[0] += v0; csq[0] += v0 * v0;
                csum[1] += v1; csq[1] += v1 * v1;
            }
        } else {
#pragma unroll
            for (int r = 0; r < 4; r++) {
                out[(rb + r) * 128 + c0] = acc0[r] + bias0;
                out[(rb + r) * 128 + c1] = acc1[r] + bias1;
            }
        }
    }

    if (MODE == 1) {
        // reduce over the 4 quads (lanes sharing l15): cols are disjoint per
        // (wave, ntl, l15), so sred has no write conflicts.
#pragma unroll
        for (int ntl = 0; ntl < 2; ntl++) {
            float s = csum[ntl];
            s += __shfl_xor(s, 16); s += __shfl_xor(s, 32);
            float q = csq[ntl];
            q += __shfl_xor(q, 16); q += __shfl_xor(q, 32);
            if (quad == 0) {
                int c = (2 * wave + ntl) * 16 + l15;
                sred[c] = s;
                sred[128 + c] = q;
            }
        }
        __syncthreads();
        atomicAdd(&stats_acc[tid], sred[tid]);
    }
}

// stats_acc[0..127]=sum, [128..255]=sumsq -> stat[0..127]=mu, [128..255]=rsig
__global__ void ebn_finalize_kernel(const float* __restrict__ acc, float invM,
                                    float* __restrict__ stat) {
    int c = threadIdx.x;  // 128
    float mu = acc[c] * invM;
    float var = acc[128 + c] * invM - mu * mu;
    stat[c] = mu;
    stat[128 + c] = rsqrtf(var + 1e-5f);
}

// ---------------------------------------------------------------------------
// BN batch stats (node path): partial sums/sumsq per channel
// ---------------------------------------------------------------------------
__global__ __launch_bounds__(256) void bn_stats_kernel(const float* __restrict__ v, long M,
                                                       float* __restrict__ partial) {
    __shared__ float lds[256];
    int tid = threadIdx.x;
    int c = tid & 127, half = tid >> 7;
    float sum = 0.f, sq = 0.f;
    for (long r = (long)blockIdx.x * 2 + half; r < M; r += (long)gridDim.x * 2) {
        float x = v[r * 128 + c];
        sum += x; sq += x * x;
    }
    lds[tid] = sum;
    __syncthreads();
    if (half == 0) sum += lds[tid + 128];
    __syncthreads();
    lds[tid] = sq;
    __syncthreads();
    if (half == 0) {
        sq += lds[tid + 128];
        partial[(long)blockIdx.x * 256 + c] = sum;
        partial[(long)blockIdx.x * 256 + 128 + c] = sq;
    }
}

__global__ void bn_finalize_kernel(const float* __restrict__ partial, int nblk, float invM,
                                   float* __restrict__ stat) {
    int c = threadIdx.x;  // 128 threads
    float s = 0.f, q = 0.f;
    for (int i = 0; i < nblk; i++) {
        s += partial[i * 256 + c];
        q += partial[i * 256 + 128 + c];
    }
    float mu = s * invM;
    float var = q * invM - mu * mu;
    stat[c] = mu;
    stat[128 + c] = rsqrtf(var + 1e-5f);
}

// io = relu(g*(vin-mu)*rsig + b) + io   (elementwise, float4)
__global__ void bn_apply_res_kernel(const float* __restrict__ vin, const float* __restrict__ stat,
                                    const float* __restrict__ g, const float* __restrict__ b,
                                    float* __restrict__ io, long M4) {
    long idx = (long)blockIdx.x * 256 + threadIdx.x;
    if (idx >= M4) return;
    int c4 = (idx & 31) << 2;
    float4 x = ((const float4*)vin)[idx];
    float4 res = ((float4*)io)[idx];
    float xv[4] = {x.x, x.y, x.z, x.w};
    float rv[4] = {res.x, res.y, res.z, res.w};
    float o[4];
#pragma unroll
    for (int t = 0; t < 4; t++) {
        int c = c4 + t;
        float y = g[c] * (xv[t] - stat[c]) * stat[128 + c] + b[c];
        o[t] = fmaxf(y, 0.f) + rv[t];
    }
    ((float4*)io)[idx] = make_float4(o[0], o[1], o[2], o[3]);
}

// ---------------------------------------------------------------------------
// fused aggregation + edge BN/relu/residual (single pass over eij, CSR by dst)
// ---------------------------------------------------------------------------
__global__ __launch_bounds__(128) void agg_bn_kernel(
    const float* __restrict__ eij, const float* __restrict__ Bx, const float* __restrict__ Ax,
    const int* __restrict__ row_ptr, const int* __restrict__ ssrc,
    const float* __restrict__ estat, const float* __restrict__ g, const float* __restrict__ b,
    const float* __restrict__ eold, const int* __restrict__ perm,
    float* __restrict__ e_out, float* __restrict__ hnew) {
    int i = blockIdx.x, c = threadIdx.x;
    int s0 = row_ptr[i], s1 = row_ptr[i + 1];
    float mu = estat[c], rs = estat[128 + c], gg = g[c], bb = b[c];
    float num = 0.f, den = 0.f;
    for (int j = s0; j < s1; j++) {
        float x = eij[(long)j * 128 + c];
        float sig = 1.f / (1.f + __expf(-x));
        num += sig * Bx[(long)ssrc[j] * 128 + c];
        den += sig;
        long er = perm ? (long)perm[j] : (long)j;
        float old = eold[er * 128 + c];
        float y = fmaxf(gg * (x - mu) * rs + bb, 0.f) + old;
        e_out[(long)j * 128 + c] = y;
    }
    long idx = (long)i * 128 + c;
    hnew[idx] = Ax[idx] + num / (den + 1e-6f);
}

// ---------------------------------------------------------------------------
// fused attention per (batch, head): scores+sph-softmax+PV, K/V in LDS
// ---------------------------------------------------------------------------
__global__ __launch_bounds__(256) void attn_kernel(const float* __restrict__ q,
                                                   const float* __restrict__ k,
                                                   const float* __restrict__ v,
                                                   const float* __restrict__ sph,
                                                   float* __restrict__ o) {
    __shared__ float k_lds[128 * 32];
    __shared__ float v_lds[128 * 32];
    int b = blockIdx.x >> 2, hd = blockIdx.x & 3;
    int tid = threadIdx.x;

    for (int i = tid; i < 1024; i += 256) {
        int t = i >> 3, d4 = i & 7;
        long gidx = (long)(b * 128 + t) * 32 + hd * 8 + d4;
        ((float4*)k_lds)[t * 8 + d4] = ((const float4*)k)[gidx];
        ((float4*)v_lds)[t * 8 + d4] = ((const float4*)v)[gidx];
    }
    __syncthreads();

    int s = tid >> 1, t0 = (tid & 1) * 64;
    float4 qreg[8];
    long qbase = (long)(b * 128 + s) * 32 + hd * 8;
#pragma unroll
    for (int j = 0; j < 8; j++) qreg[j] = ((const float4*)q)[qbase + j];
    const float* sphrow = sph + ((long)b * 128 + s) * 128 + t0;
    const float inv_sqrt_dk = 0.17677669529663687f;

    float p[64];
#pragma unroll
    for (int i = 0; i < 64; i++) {
        const float4* kr = (const float4*)&k_lds[(t0 + i) * 32];
        float acc = 0.f;
#pragma unroll
        for (int j = 0; j < 8; j++) {
            float4 kv = kr[j];
            acc += qreg[j].x * kv.x + qreg[j].y * kv.y + qreg[j].z * kv.z + qreg[j].w * kv.w;
        }
        p[i] = acc * inv_sqrt_dk * sphrow[i];
    }
    float m = -1e30f;
#pragma unroll
    for (int i = 0; i < 64; i++) m = fmaxf(m, p[i]);
    m = fmaxf(m, __shfl_xor(m, 1));
    float l = 0.f;
#pragma unroll
    for (int i = 0; i < 64; i++) {
        p[i] = __expf(p[i] - m);
        l += p[i];
    }
    l += __shfl_xor(l, 1);
    float invl = 1.f / l;

    float part[32];
#pragma unroll
    for (int d = 0; d < 32; d++) part[d] = 0.f;
#pragma unroll
    for (int i = 0; i < 64; i++) {
        float pv = p[i] * invl;
        const float4* vr = (const float4*)&v_lds[(t0 + i) * 32];
#pragma unroll
        for (int j = 0; j < 8; j++) {
            float4 vv = vr[j];
            part[4 * j + 0] += pv * vv.x;
            part[4 * j + 1] += pv * vv.y;
            part[4 * j + 2] += pv * vv.z;
            part[4 * j + 3] += pv * vv.w;
        }
    }
    int halfw = tid & 1;
    float outv[16];
#pragma unroll
    for (int d = 0; d < 32; d++) {
        float tot = part[d] + __shfl_xor(part[d], 1);
        if ((d >> 4) == halfw) outv[d & 15] = tot;
    }
    long obase = (long)(b * 128 + s) * 32 + hd * 8 + halfw * 4;
#pragma unroll
    for (int j = 0; j < 4; j++)
        ((float4*)o)[obase + j] = make_float4(outv[4 * j], outv[4 * j + 1], outv[4 * j + 2], outv[4 * j + 3]);
}

// ---------------------------------------------------------------------------
// mean-pool per graph + 3-layer MLP
// ---------------------------------------------------------------------------
__global__ __launch_bounds__(128) void pool_mlp_kernel(
    const float* __restrict__ h, const float* __restrict__ w1, const float* __restrict__ b1,
    const float* __restrict__ w2, const float* __restrict__ b2, const float* __restrict__ w3,
    const float* __restrict__ b3, float* __restrict__ out) {
    __shared__ float g[128], m1[64], m2[32];
    int b = blockIdx.x, tid = threadIdx.x;
    const float* hb = h + (long)b * 128 * 128;
    float s = 0.f;
    for (int r = 0; r < 128; r++) s += hb[r * 128 + tid];
    g[tid] = s * (1.f / 128.f);
    __syncthreads();
    if (tid < 64) {
        float a = b1[tid];
        for (int kk = 0; kk < 128; kk++) a += g[kk] * w1[kk * 64 + tid];
        m1[tid] = fmaxf(a, 0.f);
    }
    __syncthreads();
    if (tid < 32) {
        float a = b2[tid];
        for (int kk = 0; kk < 64; kk++) a += m1[kk] * w2[kk * 32 + tid];
        m2[tid] = fmaxf(a, 0.f);
    }
    __syncthreads();
    if (tid < 10) {
        float a = b3[tid];
        for (int kk = 0; kk < 32; kk++) a += m2[kk] * w3[kk * 10 + tid];
        out[b * 10 + tid] = a;
    }
}

// ---------------------------------------------------------------------------
extern "C" void kernel_launch(void* const* d_in, const int* in_sizes, int n_in,
                              void* d_out, int out_size, void* d_ws, size_t ws_size,
                              hipStream_t stream) {
    (void)in_sizes; (void)n_in; (void)out_size;
    const float* x        = (const float*)d_in[0];
    const float* pe       = (const float*)d_in[1];
    const float* edge_attr= (const float*)d_in[2];
    const float* sph      = (const float*)d_in[3];
    const float* node_w   = (const float*)d_in[4];
    const float* node_b   = (const float*)d_in[5];
    const float* pe_w     = (const float*)d_in[6];
    const float* pe_b     = (const float*)d_in[7];
    const float* conv_Aw  = (const float*)d_in[8];
    const float* conv_Ab  = (const float*)d_in[9];
    const float* conv_Bw  = (const float*)d_in[10];
    const float* conv_Bb  = (const float*)d_in[11];
    const float* conv_Cw  = (const float*)d_in[12];
    const float* conv_Cb  = (const float*)d_in[13];
    const float* conv_Dw  = (const float*)d_in[14];
    const float* conv_Db  = (const float*)d_in[15];
    const float* conv_Ew  = (const float*)d_in[16];
    const float* conv_Eb  = (const float*)d_in[17];
    const float* bnx_g    = (const float*)d_in[18];
    const float* bnx_b    = (const float*)d_in[19];
    const float* bne_g    = (const float*)d_in[20];
    const float* bne_b    = (const float*)d_in[21];
    const float* attn_w   = (const float*)d_in[22];
    const float* attn_b   = (const float*)d_in[23];
    const float* mlp1_w   = (const float*)d_in[24];
    const float* mlp1_b   = (const float*)d_in[25];
    const float* mlp2_w   = (const float*)d_in[26];
    const float* mlp2_b   = (const float*)d_in[27];
    const float* mlp3_w   = (const float*)d_in[28];
    const float* mlp3_b   = (const float*)d_in[29];
    const int*   eidx     = (const int*)d_in[30];
    const int* esrc = eidx;
    const int* edst = eidx + E_E;
    float* out = (float*)d_out;

    // workspace carve (floats first, then bf16 packs, then ints)
    float* f = (float*)d_ws;
    float* h      = f; f += (long)N_N * HID;
    float* hnew   = f; f += (long)N_N * HID;
    float* Ax     = f; f += (long)N_N * HID;   // q later
    float* Bx     = f; f += (long)N_N * HID;   // k later
    float* Dx     = f; f += (long)N_N * HID;   // v later
    float* Ex     = f; f += (long)N_N * HID;   // o later
    float* e      = f; f += (long)E_E * HID;
    float* eij    = f; f += (long)E_E * HID;
    float* partial= f; f += 512 * 256;
    float* bnxs   = f; f += 256;
    float* bnes   = f; f += 256;
    float* ebn_acc= f; f += 256;
    __bf16* Whi = (__bf16*)f;           // 24 * 16384 bf16
    __bf16* Wlo = Whi + 24 * 16384;
    int* ip = (int*)(Wlo + 24 * 16384);
    int* deg     = ip; ip += N_N;
    int* row_ptr = ip; ip += N_N + 1;
    int* cursor  = ip; ip += N_N;
    int* perm    = ip; ip += E_E;
    int* ssrc    = ip; ip += E_E;
    int* sdst    = ip; ip += E_E;
    size_t need = (size_t)((char*)ip - (char*)d_ws);
    if (ws_size < need) return;  // out stays poisoned: signals ws too small

    // ---- pack all weight matrices (bf16 hi/lo, MFMA B-frag order) ----
    WSrc24 wsrc;
    for (int l = 0; l < L_LAYERS; l++) {
        wsrc.w[l * 5 + 0] = conv_Aw + l * 16384;
        wsrc.w[l * 5 + 1] = conv_Bw + l * 16384;
        wsrc.w[l * 5 + 2] = conv_Cw + l * 16384;
        wsrc.w[l * 5 + 3] = conv_Dw + l * 16384;
        wsrc.w[l * 5 + 4] = conv_Ew + l * 16384;
    }
    for (int m = 0; m < 4; m++) wsrc.w[20 + m] = attn_w + m * 16384;
    pack_w_kernel<<<24, 256, 0, stream>>>(wsrc, Whi, Wlo);

    // ---- build CSR by dst ----
    zero_int_kernel<<<(N_N + 255) / 256, 256, 0, stream>>>(deg, N_N);
    hist_kernel<<<E_E / 256, 256, 0, stream>>>(edst, deg);
    scan_kernel<<<1, 1024, 0, stream>>>(deg, row_ptr, cursor);
    scatter_kernel<<<E_E / 256, 256, 0, stream>>>(esrc, edst, cursor, perm, ssrc, sdst);

    embed_kernel<<<N_N * HID / 256, 256, 0, stream>>>(x, pe, node_w, node_b, pe_w, pe_b, h);

    for (int l = 0; l < L_LAYERS; l++) {
        zero_int_kernel<<<1, 256, 0, stream>>>((int*)ebn_acc, 256);

        // ABDE node GEMMs batched: y selects matrix. 4 tiles/block.
        Sel4 selN;
        selN.o[0] = Ax; selN.b[0] = conv_Ab + l * 128; selN.slot[0] = l * 5 + 0;
        selN.o[1] = Bx; selN.b[1] = conv_Bb + l * 128; selN.slot[1] = l * 5 + 1;
        selN.o[2] = Dx; selN.b[2] = conv_Db + l * 128; selN.slot[2] = l * 5 + 3;
        selN.o[3] = Ex; selN.b[3] = conv_Eb + l * 128; selN.slot[3] = l * 5 + 4;
        mfma_gemm_ws_kernel<0><<<dim3(256, 4), 256, 0, stream>>>(
            h, nullptr, Whi, Wlo, selN, nullptr, nullptr, nullptr, nullptr, nullptr, N_N / 16);

        // edge GEMM: eij = e@Cw + Cb + Dx[dst] + Ex[src], fused BN stats.
        // 16 tiles/block -> 16x B-frag reuse from registers.
        const float* Asrc = (l == 0) ? edge_attr : e;
        const int* permA = (l == 0) ? perm : nullptr;
        Sel4 selE;
        selE.o[0] = eij; selE.b[0] = conv_Cb + l * 128; selE.slot[0] = l * 5 + 2;
        selE.o[1] = selE.o[2] = selE.o[3] = eij;
        selE.b[1] = selE.b[2] = selE.b[3] = selE.b[0];
        selE.slot[1] = selE.slot[2] = selE.slot[3] = selE.slot[0];
        mfma_gemm_ws_kernel<1><<<dim3(1024, 1), 256, 0, stream>>>(
            Asrc, permA, Whi, Wlo, selE, Dx, Ex, sdst, ssrc, ebn_acc, E_E / 16);

        ebn_finalize_kernel<<<1, 128, 0, stream>>>(ebn_acc, 1.f / E_E, bnes);

        // fused: aggregation (hnew) + edge BN/relu/residual (e update)
        const float* eoldSrc = (l == 0) ? edge_attr : e;
        const int* permE = (l == 0) ? perm : nullptr;
        agg_bn_kernel<<<N_N, 128, 0, stream>>>(eij, Bx, Ax, row_ptr, ssrc, bnes,
                                               bne_g + l * 128, bne_b + l * 128,
                                               eoldSrc, permE, e, hnew);

        bn_stats_kernel<<<128, 256, 0, stream>>>(hnew, (long)N_N, partial);
        bn_finalize_kernel<<<1, 128, 0, stream>>>(partial, 128, 1.f / N_N, bnxs);
        bn_apply_res_kernel<<<N_N * 32 / 256, 256, 0, stream>>>(
            hnew, bnxs, bnx_g + l * 128, bnx_b + l * 128, h, (long)N_N * 32);

        // qkv batched: q=Ax, k=Bx, v=Dx
        Sel4 selQ;
        selQ.o[0] = Ax; selQ.b[0] = attn_b;       selQ.slot[0] = 20;
        selQ.o[1] = Bx; selQ.b[1] = attn_b + 128; selQ.slot[1] = 21;
        selQ.o[2] = Dx; selQ.b[2] = attn_b + 256; selQ.slot[2] = 22;
        selQ.o[3] = Dx; selQ.b[3] = attn_b + 256; selQ.slot[3] = 22;
        mfma_gemm_ws_kernel<0><<<dim3(340, 3), 256, 0, stream>>>(
            h, nullptr, Whi, Wlo, selQ, nullptr, nullptr, nullptr, nullptr, nullptr, N_N / 16);

        attn_kernel<<<B_G * HEADS, 256, 0, stream>>>(Ax, Bx, Dx, sph, Ex);

        // output projection: h = o @ Wproj + b
        Sel4 selP;
        selP.o[0] = h; selP.b[0] = attn_b + 384; selP.slot[0] = 23;
        selP.o[1] = selP.o[2] = selP.o[3] = h;
        selP.b[1] = selP.b[2] = selP.b[3] = selP.b[0];
        selP.slot[1] = selP.slot[2] = selP.slot[3] = selP.slot[0];
        mfma_gemm_ws_kernel<0><<<dim3(512, 1), 256, 0, stream>>>(
            Ex, nullptr, Whi, Wlo, selP, nullptr, nullptr, nullptr, nullptr, nullptr, N_N / 16);
    }

    pool_mlp_kernel<<<B_G, 128, 0, stream>>>(h, mlp1_w, mlp1_b, mlp2_w, mlp2_b, mlp3_w, mlp3_b, out);
}